// Round 3
// baseline (303.665 us; speedup 1.0000x reference)
//
#include <hip/hip_runtime.h>
#include <math.h>

// Problem constants (MicroGPT)
constexpr int Bc  = 16;
constexpr int Tc  = 2048;
constexpr int Cc  = 16;
constexpr int Hc  = 2;
constexpr int HSc = 8;
constexpr int Lc  = 2;
constexpr int Vc  = 256;
constexpr int BT  = Bc * Tc;          // 32768 tokens
constexpr float EPSc = 1e-5f;

// Attention tiling: K-chunk split + 8 CONSECUTIVE queries/thread.
// History: 2q/thr LDS-b64 = 56us (LDS-pipe-bound: 8 ds_read/step, 64 LDS-cyc
// vs 20 VALU-cyc/SIMD-share); scalar-pipe K/V = 86us (latency-bound).
// Now: 8q/thr amortizes K/V 4x, float4 LDS reads halve instr count ->
// 4 ds_read_b128/step (~52 LDS-cyc) vs ~75 VALU-cyc/SIMD-share = VALU-bound.
constexpr int KC  = 128;              // keys per chunk (LDS tile)
constexpr int NCH = Tc / KC;          // 16 chunks (pacc layout - do not change)
constexpr int QB  = 2048;             // queries per block (256 thr x 8)
constexpr int NQ  = 8;                // queries per thread

__device__ inline float shx(float v, int m) { return __shfl_xor(v, m, 64); }

// ---------------------------------------------------------------------------
// LN helper
// ---------------------------------------------------------------------------
__device__ inline void layernorm16(const float* xr, float* h,
                                   const float* g, const float* b) {
  float m = 0.f;
#pragma unroll
  for (int c = 0; c < Cc; c++) m += xr[c];
  m *= (1.f / Cc);
  float var = 0.f;
#pragma unroll
  for (int c = 0; c < Cc; c++) { float d = xr[c] - m; var += d * d; }
  var *= (1.f / Cc);
  float rs = rsqrtf(var + EPSc);
#pragma unroll
  for (int c = 0; c < Cc; c++) h[c] = (xr[c] - m) * rs * g[c] + b[c];
}

// ---------------------------------------------------------------------------
// 4-lane-coop QKV: lane j computes s={2j,2j+1} of every (head, q/k/v) vector
// ---------------------------------------------------------------------------
__device__ inline void qkv_store_lane(const float* h, const float* swq,
                                      const float* swk, const float* swv,
                                      int bb, int tt, int j,
                                      float* __restrict__ q,
                                      float* __restrict__ k,
                                      float* __restrict__ v) {
#pragma unroll
  for (int hh = 0; hh < Hc; hh++) {
    float q0 = 0.f, q1 = 0.f, k0 = 0.f, k1 = 0.f, v0 = 0.f, v1 = 0.f;
#pragma unroll
    for (int c = 0; c < Cc; c++) {
      float hv = h[c];
      const float* wqp = swq + (hh * Cc + c) * HSc + 2 * j;
      const float* wkp = swk + (hh * Cc + c) * HSc + 2 * j;
      const float* wvp = swv + (hh * Cc + c) * HSc + 2 * j;
      q0 += hv * wqp[0]; q1 += hv * wqp[1];
      k0 += hv * wkp[0]; k1 += hv * wkp[1];
      v0 += hv * wvp[0]; v1 += hv * wvp[1];
    }
    long base = ((long)(bb * Hc + hh) * Tc + tt) * HSc;
    ((float2*)(q + base))[j] = make_float2(q0, q1);
    ((float2*)(k + base))[j] = make_float2(k0, k1);
    ((float2*)(v + base))[j] = make_float2(v0, v1);
  }
}

// ---------------------------------------------------------------------------
// K1) x = tok_emb[idx] + pos_emb ; h = LN1(x) ; q,k,v = h @ W  (layer 0)
// ---------------------------------------------------------------------------
__global__ __launch_bounds__(256, 4) void embed_ln_qkv_kernel(
    const int* __restrict__ idx, const float* __restrict__ tok,
    const float* __restrict__ pos,
    const float* __restrict__ wq, const float* __restrict__ wk,
    const float* __restrict__ wv,
    const float* __restrict__ g, const float* __restrict__ b,
    float* __restrict__ x, float* __restrict__ q, float* __restrict__ k,
    float* __restrict__ v) {
  __shared__ float swq[256], swk[256], swv[256], sg[Cc], sb[Cc];
  int tid = threadIdx.x;
  swq[tid] = wq[tid];
  swk[tid] = wk[tid];
  swv[tid] = wv[tid];
  if (tid < Cc) { sg[tid] = g[tid]; sb[tid] = b[tid]; }
  __syncthreads();

  int tk = blockIdx.x * 64 + (tid >> 2);
  int j  = tid & 3;
  int tt = tk & (Tc - 1);
  int bb = tk >> 11;
  int id = idx[tk];
  float xr[Cc];
  const float4* te = (const float4*)(tok + id * Cc);
  const float4* pe = (const float4*)(pos + tt * Cc);
#pragma unroll
  for (int i = 0; i < 4; i++) {
    float4 a = te[i], p = pe[i];
    xr[4*i] = a.x + p.x; xr[4*i+1] = a.y + p.y;
    xr[4*i+2] = a.z + p.z; xr[4*i+3] = a.w + p.w;
  }
  ((float4*)(x + (long)tk * Cc))[j] =
      make_float4(xr[4*j], xr[4*j+1], xr[4*j+2], xr[4*j+3]);
  float h[Cc];
  layernorm16(xr, h, sg, sb);
  qkv_store_lane(h, swq, swk, swv, bb, tt, j, q, k, v);
}

// ---------------------------------------------------------------------------
// K2) Causal flash attention. K-chunk split, 8 consecutive queries/thread,
//     K/V staged in LDS, float4 reads (4 ds_read_b128 per key-step serve
//     8 q x 64 lanes). Per-wave uniform loop bounds via readfirstlane keep
//     the hot loop unmasked; <=KC-step masked epilogue handles the diagonal.
//     Writes UNNORMALIZED partials (acc[8], l) per (query, chunk).
// ---------------------------------------------------------------------------
__global__ __launch_bounds__(256, 2) void attn_kernel(
    const float* __restrict__ q, const float* __restrict__ k,
    const float* __restrict__ v, float* __restrict__ pacc,
    float* __restrict__ pl) {
  int bh = blockIdx.x;            // 0..31
  int ch = blockIdx.y;            // 0..15
  int k0 = ch * KC;

  __shared__ float sk[KC * HSc], sv[KC * HSc];
  int tid = threadIdx.x;
  {
    const float4* ksrc = (const float4*)(k + ((long)bh * Tc + k0) * HSc);
    const float4* vsrc = (const float4*)(v + ((long)bh * Tc + k0) * HSc);
    ((float4*)sk)[tid] = ksrc[tid];      // KC*HSc/4 == 256 == blockDim
    ((float4*)sv)[tid] = vsrc[tid];
  }
  __syncthreads();

  int q0 = NQ * tid;              // 8 consecutive queries q0..q0+7
  int t1 = q0 - k0;               // key u unmasked for ALL 8 iff u<=t1

  // wave-uniform bounds (lane 0 has the smallest q0 in the wave)
  int t1f   = __builtin_amdgcn_readfirstlane(t1);
  int nfull = t1f + 1;            // u < nfull: unmasked for every lane/query
  if (nfull < 0) nfull = 0;
  if (nfull > KC) nfull = KC;
  int nend  = t1f + 64 * NQ;      // last lane t1 = t1f+504, +8 for i=7
  if (nend < 0) nend = 0;
  if (nend > KC) nend = KC;
  if (nend == 0) return;          // whole wave in causal future (after barrier)

  const float pre = 0.35355339059327373f * 1.4426950408889634f;
  float qr[NQ][8];
  float acc[NQ][8];
  float l4[NQ];
  {
    const float4* qp = (const float4*)(q + ((long)bh * Tc + q0) * HSc);
#pragma unroll
    for (int i = 0; i < NQ; i++) {
      float4 a = qp[i * 2], b = qp[i * 2 + 1];
      qr[i][0] = a.x * pre; qr[i][1] = a.y * pre;
      qr[i][2] = a.z * pre; qr[i][3] = a.w * pre;
      qr[i][4] = b.x * pre; qr[i][5] = b.y * pre;
      qr[i][6] = b.z * pre; qr[i][7] = b.w * pre;
#pragma unroll
      for (int c = 0; c < 8; c++) acc[i][c] = 0.f;
      l4[i] = 0.f;
    }
  }

  const float4* skp = (const float4*)sk;
  const float4* svp = (const float4*)sv;

#define ATTN_STEP(u, MASKED)                                              \
  {                                                                       \
    float4 ka = skp[(u) * 2], kb = skp[(u) * 2 + 1];                      \
    float4 va = svp[(u) * 2], vb = svp[(u) * 2 + 1];                      \
    _Pragma("unroll")                                                     \
    for (int i = 0; i < NQ; i++) {                                        \
      float s = qr[i][0] * ka.x + qr[i][1] * ka.y + qr[i][2] * ka.z +     \
                qr[i][3] * ka.w + qr[i][4] * kb.x + qr[i][5] * kb.y +     \
                qr[i][6] * kb.z + qr[i][7] * kb.w;                        \
      float p = __builtin_amdgcn_exp2f(s);                                \
      if (MASKED) p = ((u) - t1 <= i) ? p : 0.f;                          \
      l4[i] += p;                                                         \
      acc[i][0] += p * va.x; acc[i][1] += p * va.y;                       \
      acc[i][2] += p * va.z; acc[i][3] += p * va.w;                       \
      acc[i][4] += p * vb.x; acc[i][5] += p * vb.y;                       \
      acc[i][6] += p * vb.z; acc[i][7] += p * vb.w;                       \
    }                                                                     \
  }

#pragma unroll 2
  for (int u = 0; u < nfull; u++) ATTN_STEP(u, false)
  for (int u = nfull; u < nend; u++) ATTN_STEP(u, true)
#undef ATTN_STEP

  long rec = (long)(bh * NCH + ch) * Tc + q0;
#pragma unroll
  for (int i = 0; i < NQ; i++) {
    if (t1 + i + 1 > 0) {
      float4* pa = (float4*)(pacc + (rec + i) * 8);
      pa[0] = make_float4(acc[i][0], acc[i][1], acc[i][2], acc[i][3]);
      pa[1] = make_float4(acc[i][4], acc[i][5], acc[i][6], acc[i][7]);
      pl[rec + i] = l4[i];
    }
  }
}

// ---------------------------------------------------------------------------
// 4-lane cooperative tail: reduce partials -> o ; x += o@wo^T ; x += MLP(LN2)
// Lane roles (j = lane&3):
//   A: head j&1, chunks (j>>1)::2   -> shfl_xor combine
//   B: proj outputs c = 4j..4j+3    -> shfl_xor replicate
//   C: MLP hidden units j*16..+15   -> shfl_xor combine
// LDS layouts: swo [16][17] padded, sw1 [64][17] padded, sw2 [16][64].
// ---------------------------------------------------------------------------
__device__ inline void coop_tail(
    const float* __restrict__ pacc, const float* __restrict__ pl,
    const float* swo, const float* sw1, const float* sw2,
    const float* sg2, const float* sb2, int bb, int tt, int j, float* xr) {
  // --- A: attention partial reduce
  int hh  = j & 1;
  int bh  = bb * Hc + hh;
  int nch = tt / KC + 1;
  float o8[8] = {0,0,0,0,0,0,0,0};
  float l = 0.f;
#pragma unroll 2
  for (int ch = (j >> 1); ch < nch; ch += 2) {
    long rec = (long)(bh * NCH + ch) * Tc + tt;
    const float4* pa = (const float4*)(pacc + rec * 8);
    float4 a = pa[0], b = pa[1];
    o8[0]+=a.x; o8[1]+=a.y; o8[2]+=a.z; o8[3]+=a.w;
    o8[4]+=b.x; o8[5]+=b.y; o8[6]+=b.z; o8[7]+=b.w;
    l += pl[rec];
  }
#pragma unroll
  for (int s = 0; s < 8; s++) o8[s] += shx(o8[s], 2);
  l += shx(l, 2);
  float inv = 1.f / l;
  float own[8], oth[8];
#pragma unroll
  for (int s = 0; s < 8; s++) own[s] = o8[s] * inv;
#pragma unroll
  for (int s = 0; s < 8; s++) oth[s] = shx(own[s], 1);
  float orow[Cc];
#pragma unroll
  for (int s = 0; s < 8; s++) {
    orow[s]     = (hh == 0) ? own[s] : oth[s];
    orow[8 + s] = (hh == 0) ? oth[s] : own[s];
  }
  // --- B: proj, c = 4j..4j+3
  float xc[4];
#pragma unroll
  for (int qq = 0; qq < 4; qq++) {
    int c = 4 * j + qq;
    float acc = xr[c];
#pragma unroll
    for (int kk = 0; kk < Cc; kk++) acc += orow[kk] * swo[c * 17 + kk];
    xc[qq] = acc;
  }
  {
    float p[4];
#pragma unroll
    for (int qq = 0; qq < 4; qq++) p[qq] = shx(xc[qq], 1);
    bool lo = (j & 1) == 0;
    float a8[8], b8[8];
#pragma unroll
    for (int qq = 0; qq < 4; qq++) {
      a8[qq]     = lo ? xc[qq] : p[qq];
      a8[4 + qq] = lo ? p[qq] : xc[qq];
    }
#pragma unroll
    for (int s = 0; s < 8; s++) b8[s] = shx(a8[s], 2);
    bool lo2 = (j & 2) == 0;
#pragma unroll
    for (int s = 0; s < 8; s++) {
      xr[s]     = lo2 ? a8[s] : b8[s];
      xr[8 + s] = lo2 ? b8[s] : a8[s];
    }
  }
  // --- C: MLP, hidden units j*16..j*16+15
  float h[Cc];
  layernorm16(xr, h, sg2, sb2);
  float r[Cc];
#pragma unroll
  for (int c = 0; c < Cc; c++) r[c] = 0.f;
#pragma unroll
  for (int i = 0; i < 16; i++) {
    int jj = j * 16 + i;
    float acc = 0.f;
#pragma unroll
    for (int c = 0; c < Cc; c++) acc += h[c] * sw1[jj * 17 + c];
    acc = fmaxf(acc, 0.f);
#pragma unroll
    for (int c = 0; c < Cc; c++) r[c] += acc * sw2[c * 64 + jj];
  }
#pragma unroll
  for (int c = 0; c < Cc; c++) r[c] += shx(r[c], 1);
#pragma unroll
  for (int c = 0; c < Cc; c++) r[c] += shx(r[c], 2);
#pragma unroll
  for (int c = 0; c < Cc; c++) xr[c] += r[c];
}

// ---------------------------------------------------------------------------
// K3) layer-l epilogue + layer-(l+1) LN1+QKV  (4-lane coop, 512 blocks)
// ---------------------------------------------------------------------------
__global__ __launch_bounds__(256, 4) void red_mid_kernel(
    const float* __restrict__ pacc, const float* __restrict__ pl,
    const float* __restrict__ wo, const float* __restrict__ g2,
    const float* __restrict__ b2, const float* __restrict__ w1,
    const float* __restrict__ w2,
    const float* __restrict__ wq, const float* __restrict__ wk,
    const float* __restrict__ wv, const float* __restrict__ g1,
    const float* __restrict__ b1,
    float* __restrict__ x, float* __restrict__ q, float* __restrict__ k,
    float* __restrict__ v) {
  __shared__ float swo[16 * 17], sw1[64 * 17], sw2[1024];
  __shared__ float swq[256], swk[256], swv[256];
  __shared__ float sg2[Cc], sb2[Cc], sg1[Cc], sb1[Cc];
  int tid = threadIdx.x;
  swq[tid] = wq[tid]; swk[tid] = wk[tid]; swv[tid] = wv[tid];
  { int rr = tid >> 4, c = tid & 15; swo[rr * 17 + c] = wo[tid]; }
#pragma unroll
  for (int t = tid; t < 1024; t += 256) {
    int jj = t >> 4, c = t & 15;
    sw1[jj * 17 + c] = w1[t];
    sw2[t] = w2[t];
  }
  if (tid < Cc) {
    sg2[tid] = g2[tid]; sb2[tid] = b2[tid];
    sg1[tid] = g1[tid]; sb1[tid] = b1[tid];
  }
  __syncthreads();

  int tk = blockIdx.x * 64 + (tid >> 2);
  int j  = tid & 3;
  int bb = tk >> 11, tt = tk & (Tc - 1);
  float xr[Cc];
  const float4* xp = (const float4*)(x + (long)tk * Cc);
#pragma unroll
  for (int i = 0; i < 4; i++) {
    float4 a = xp[i];
    xr[4*i]=a.x; xr[4*i+1]=a.y; xr[4*i+2]=a.z; xr[4*i+3]=a.w;
  }
  coop_tail(pacc, pl, swo, sw1, sw2, sg2, sb2, bb, tt, j, xr);
  ((float4*)(x + (long)tk * Cc))[j] =
      make_float4(xr[4*j], xr[4*j+1], xr[4*j+2], xr[4*j+3]);
  float h[Cc];
  layernorm16(xr, h, sg1, sb1);
  qkv_store_lane(h, swq, swk, swv, bb, tt, j, q, k, v);
}

// ---------------------------------------------------------------------------
// K5) final-layer epilogue + LNf + tied lm_head  (4-lane coop + head phase)
// ---------------------------------------------------------------------------
__global__ __launch_bounds__(256, 4) void red_lnf_head_kernel(
    const float* __restrict__ pacc, const float* __restrict__ pl,
    const float* __restrict__ wo, const float* __restrict__ g2,
    const float* __restrict__ b2, const float* __restrict__ w1,
    const float* __restrict__ w2, const float* __restrict__ gf,
    const float* __restrict__ bf,
    const float* __restrict__ x, const float* __restrict__ tok,
    float* __restrict__ out) {
  __shared__ float swo[16 * 17], sw1[64 * 17], sw2[1024];
  __shared__ float sg2[Cc], sb2[Cc], sgf[Cc], sbf[Cc];
  __shared__ float sh[64 * Cc];
  int tid = threadIdx.x;
  { int rr = tid >> 4, c = tid & 15; swo[rr * 17 + c] = wo[tid]; }
#pragma unroll
  for (int t = tid; t < 1024; t += 256) {
    int jj = t >> 4, c = t & 15;
    sw1[jj * 17 + c] = w1[t];
    sw2[t] = w2[t];
  }
  if (tid < Cc) {
    sg2[tid] = g2[tid]; sb2[tid] = b2[tid];
    sgf[tid] = gf[tid]; sbf[tid] = bf[tid];
  }
  __syncthreads();

  int tk = blockIdx.x * 64 + (tid >> 2);
  int j  = tid & 3;
  int bb = tk >> 11, tt = tk & (Tc - 1);
  float xr[Cc];
  const float4* xp = (const float4*)(x + (long)tk * Cc);
#pragma unroll
  for (int i = 0; i < 4; i++) {
    float4 a = xp[i];
    xr[4*i]=a.x; xr[4*i+1]=a.y; xr[4*i+2]=a.z; xr[4*i+3]=a.w;
  }
  coop_tail(pacc, pl, swo, sw1, sw2, sg2, sb2, bb, tt, j, xr);
  float h[Cc];
  layernorm16(xr, h, sgf, sbf);
  ((float4*)(sh + (tid >> 2) * Cc))[j] =
      make_float4(h[4*j], h[4*j+1], h[4*j+2], h[4*j+3]);
  __syncthreads();

  // head phase: thread = vocab id, 64 tokens from LDS (broadcast reads)
  float4 e0, e1, e2, e3;
  {
    const float4* ep = (const float4*)(tok + tid * Cc);
    e0 = ep[0]; e1 = ep[1]; e2 = ep[2]; e3 = ep[3];
  }
  int row0 = blockIdx.x * 64;
#pragma unroll 4
  for (int t = 0; t < 64; t++) {
    const float4* hp = (const float4*)(sh + t * Cc);
    float4 h0 = hp[0], h1 = hp[1], h2 = hp[2], h3 = hp[3];
    float acc = h0.x*e0.x + h0.y*e0.y + h0.z*e0.z + h0.w*e0.w
              + h1.x*e1.x + h1.y*e1.y + h1.z*e1.z + h1.w*e1.w
              + h2.x*e2.x + h2.y*e2.y + h2.z*e2.z + h2.w*e2.w
              + h3.x*e3.x + h3.y*e3.y + h3.z*e3.z + h3.w*e3.w;
    out[(long)(row0 + t) * Vc + tid] = acc;
  }
}

// ---------------------------------------------------------------------------
// launcher
// ---------------------------------------------------------------------------
extern "C" void kernel_launch(void* const* d_in, const int* in_sizes, int n_in,
                              void* d_out, int out_size, void* d_ws,
                              size_t ws_size, hipStream_t stream) {
  const int*   idx  = (const int*)  d_in[0];
  const float* tok  = (const float*)d_in[1];
  const float* pos  = (const float*)d_in[2];
  const float* wq   = (const float*)d_in[3];
  const float* wk   = (const float*)d_in[4];
  const float* wv   = (const float*)d_in[5];
  const float* wo   = (const float*)d_in[6];
  const float* ln1g = (const float*)d_in[7];
  const float* ln1b = (const float*)d_in[8];
  const float* ln2g = (const float*)d_in[9];
  const float* ln2b = (const float*)d_in[10];
  const float* w1   = (const float*)d_in[11];
  const float* w2   = (const float*)d_in[12];
  const float* lnfg = (const float*)d_in[13];
  const float* lnfb = (const float*)d_in[14];
  float* out = (float*)d_out;

  // workspace layout (floats):
  // x: 2MB | q,k,v: 2MB each | pacc: 32MB | pl: 4MB
  float* x    = (float*)d_ws;
  float* q    = x + (long)BT * Cc;
  float* k    = q + (long)Bc * Hc * Tc * HSc;
  float* v    = k + (long)Bc * Hc * Tc * HSc;
  float* pacc = v + (long)Bc * Hc * Tc * HSc;
  float* pl   = pacc + (long)Bc * Hc * NCH * Tc * HSc;

  dim3 agrid(Bc * Hc, NCH);

  embed_ln_qkv_kernel<<<BT / 64, 256, 0, stream>>>(
      idx, tok, pos, wq, wk, wv, ln1g, ln1b, x, q, k, v);
  attn_kernel<<<agrid, 256, 0, stream>>>(q, k, v, pacc, pl);
  red_mid_kernel<<<BT / 64, 256, 0, stream>>>(
      pacc, pl, wo, ln2g, ln2b, w1, w2,
      wq + Hc * Cc * HSc, wk + Hc * Cc * HSc, wv + Hc * Cc * HSc,
      ln1g + Cc, ln1b + Cc, x, q, k, v);
  attn_kernel<<<agrid, 256, 0, stream>>>(q, k, v, pacc, pl);
  red_lnf_head_kernel<<<BT / 64, 256, 0, stream>>>(
      pacc, pl, wo + Cc * Cc, ln2g + Cc, ln2b + Cc,
      w1 + 4 * Cc * Cc, w2 + 4 * Cc * Cc, lnfg, lnfb, x, tok, out);
}

// Round 4
// 234.318 us; speedup vs baseline: 1.2960x; 1.2960x over previous
//
#include <hip/hip_runtime.h>
#include <math.h>

// Problem constants (MicroGPT)
constexpr int Bc  = 16;
constexpr int Tc  = 2048;
constexpr int Cc  = 16;
constexpr int Hc  = 2;
constexpr int HSc = 8;
constexpr int Lc  = 2;
constexpr int Vc  = 256;
constexpr int BT  = Bc * Tc;          // 32768 tokens
constexpr float EPSc = 1e-5f;

// Attention: K-chunk split, 4 consecutive queries/thread, f2/pk-FMA math
// (R3 scalar form issued 1.8x the VALU cycles -> keep ext-vector f2),
// b128 LDS reads, and a 1D grid ordered LARGEST-BLOCK-FIRST:
// R0's 3D grid launched the 256 full-length blocks LAST -> tail at low
// occupancy (15%) was the real limiter, not any single pipe.
// Item sizes per (b,h): {512 x12, 384 x4, 256 x4, 128 x4} wave-steps = 9216,
// which greedy-schedules to ~1152/CU when issued in descending order.
constexpr int KC  = 128;              // keys per chunk (LDS tile)
constexpr int NCH = Tc / KC;          // 16 chunks (pacc layout - do not change)
constexpr int QB  = 1024;             // queries per block (256 thr x 4)
constexpr int NQ  = 4;                // queries per thread
constexpr int NIT = 24;               // useful (qb,ch) items per (b,h)

typedef float f2 __attribute__((ext_vector_type(2)));
typedef float f4 __attribute__((ext_vector_type(4)));

__device__ inline float shx(float v, int m) { return __shfl_xor(v, m, 64); }

// ---------------------------------------------------------------------------
// LN helper
// ---------------------------------------------------------------------------
__device__ inline void layernorm16(const float* xr, float* h,
                                   const float* g, const float* b) {
  float m = 0.f;
#pragma unroll
  for (int c = 0; c < Cc; c++) m += xr[c];
  m *= (1.f / Cc);
  float var = 0.f;
#pragma unroll
  for (int c = 0; c < Cc; c++) { float d = xr[c] - m; var += d * d; }
  var *= (1.f / Cc);
  float rs = rsqrtf(var + EPSc);
#pragma unroll
  for (int c = 0; c < Cc; c++) h[c] = (xr[c] - m) * rs * g[c] + b[c];
}

// ---------------------------------------------------------------------------
// 4-lane-coop QKV: lane j computes s={2j,2j+1} of every (head, q/k/v) vector
// ---------------------------------------------------------------------------
__device__ inline void qkv_store_lane(const float* h, const float* swq,
                                      const float* swk, const float* swv,
                                      int bb, int tt, int j,
                                      float* __restrict__ q,
                                      float* __restrict__ k,
                                      float* __restrict__ v) {
#pragma unroll
  for (int hh = 0; hh < Hc; hh++) {
    float q0 = 0.f, q1 = 0.f, k0 = 0.f, k1 = 0.f, v0 = 0.f, v1 = 0.f;
#pragma unroll
    for (int c = 0; c < Cc; c++) {
      float hv = h[c];
      const float* wqp = swq + (hh * Cc + c) * HSc + 2 * j;
      const float* wkp = swk + (hh * Cc + c) * HSc + 2 * j;
      const float* wvp = swv + (hh * Cc + c) * HSc + 2 * j;
      q0 += hv * wqp[0]; q1 += hv * wqp[1];
      k0 += hv * wkp[0]; k1 += hv * wkp[1];
      v0 += hv * wvp[0]; v1 += hv * wvp[1];
    }
    long base = ((long)(bb * Hc + hh) * Tc + tt) * HSc;
    ((float2*)(q + base))[j] = make_float2(q0, q1);
    ((float2*)(k + base))[j] = make_float2(k0, k1);
    ((float2*)(v + base))[j] = make_float2(v0, v1);
  }
}

// ---------------------------------------------------------------------------
// K1) x = tok_emb[idx] + pos_emb ; h = LN1(x) ; q,k,v = h @ W  (layer 0)
// ---------------------------------------------------------------------------
__global__ __launch_bounds__(256, 4) void embed_ln_qkv_kernel(
    const int* __restrict__ idx, const float* __restrict__ tok,
    const float* __restrict__ pos,
    const float* __restrict__ wq, const float* __restrict__ wk,
    const float* __restrict__ wv,
    const float* __restrict__ g, const float* __restrict__ b,
    float* __restrict__ x, float* __restrict__ q, float* __restrict__ k,
    float* __restrict__ v) {
  __shared__ float swq[256], swk[256], swv[256], sg[Cc], sb[Cc];
  int tid = threadIdx.x;
  swq[tid] = wq[tid];
  swk[tid] = wk[tid];
  swv[tid] = wv[tid];
  if (tid < Cc) { sg[tid] = g[tid]; sb[tid] = b[tid]; }
  __syncthreads();

  int tk = blockIdx.x * 64 + (tid >> 2);
  int j  = tid & 3;
  int tt = tk & (Tc - 1);
  int bb = tk >> 11;
  int id = idx[tk];
  float xr[Cc];
  const float4* te = (const float4*)(tok + id * Cc);
  const float4* pe = (const float4*)(pos + tt * Cc);
#pragma unroll
  for (int i = 0; i < 4; i++) {
    float4 a = te[i], p = pe[i];
    xr[4*i] = a.x + p.x; xr[4*i+1] = a.y + p.y;
    xr[4*i+2] = a.z + p.z; xr[4*i+3] = a.w + p.w;
  }
  ((float4*)(x + (long)tk * Cc))[j] =
      make_float4(xr[4*j], xr[4*j+1], xr[4*j+2], xr[4*j+3]);
  float h[Cc];
  layernorm16(xr, h, sg, sb);
  qkv_store_lane(h, swq, swk, swv, bb, tt, j, q, k, v);
}

// ---------------------------------------------------------------------------
// K2) Causal flash attention. 1D grid: blockIdx.x = item*32 + bh, item in
//     descending-work order so long blocks launch first (balanced tail).
//     4 consecutive queries/thread, K/V staged in LDS, b128 reads, f2 math.
//     Per-wave uniform loop bounds via readfirstlane; masked epilogue.
//     Writes UNNORMALIZED partials (acc[8], l) per (query, chunk).
// ---------------------------------------------------------------------------
__global__ __launch_bounds__(256, 4) void attn_kernel(
    const float* __restrict__ q, const float* __restrict__ k,
    const float* __restrict__ v, float* __restrict__ pacc,
    float* __restrict__ pl) {
  int it = blockIdx.x >> 5;       // 0..23, descending work
  int bh = blockIdx.x & 31;       // 0..31
  int qb, ch;
  if (it < 8) { qb = 1; ch = it; }                 // full blocks (512 steps)
  else {
    int g = (it - 8) >> 2, r = (it - 8) & 3;       // diagonal pairs, large->small
    if (r < 2) { qb = 0; ch = 2 * g + r; }
    else       { qb = 1; ch = 8 + 2 * g + (r - 2); }
  }
  int k0 = ch * KC;

  __shared__ float sk[KC * HSc], sv[KC * HSc];
  int tid = threadIdx.x;
  {
    const float4* ksrc = (const float4*)(k + ((long)bh * Tc + k0) * HSc);
    const float4* vsrc = (const float4*)(v + ((long)bh * Tc + k0) * HSc);
    ((float4*)sk)[tid] = ksrc[tid];      // KC*HSc/4 == 256 == blockDim
    ((float4*)sv)[tid] = vsrc[tid];
  }
  __syncthreads();

  int q0 = qb * QB + NQ * tid;    // 4 consecutive queries q0..q0+3
  int t1 = q0 - k0;               // key u unmasked for ALL 4 iff u<=t1

  // wave-uniform bounds (lane 0 has the smallest q0 in the wave)
  int t1f   = __builtin_amdgcn_readfirstlane(t1);
  int nfull = t1f + 1;            // u < nfull: unmasked for every lane/query
  if (nfull < 0) nfull = 0;
  if (nfull > KC) nfull = KC;
  int nend  = t1f + 64 * NQ;      // last lane t1 = t1f+252, +4 for i=3
  if (nend < 0) nend = 0;
  if (nend > KC) nend = KC;
  if (nend == 0) return;          // whole wave in causal future (after barrier)

  const float pre = 0.35355339059327373f * 1.4426950408889634f;
  f2 qr[NQ][4];
  f2 acc[NQ][4];
  float l4[NQ];
  {
    const f2* qp = (const f2*)(q + ((long)bh * Tc + q0) * HSc);
#pragma unroll
    for (int i = 0; i < NQ; i++) {
#pragma unroll
      for (int jj = 0; jj < 4; jj++) {
        qr[i][jj] = qp[i * 4 + jj] * pre;
        acc[i][jj] = {0.f, 0.f};
      }
      l4[i] = 0.f;
    }
  }

  const f4* skp = (const f4*)sk;
  const f4* svp = (const f4*)sv;

#define ATTN_STEP(u, MASKED)                                              \
  {                                                                       \
    f4 kA = skp[(u) * 2], kB = skp[(u) * 2 + 1];                          \
    f4 vA = svp[(u) * 2], vB = svp[(u) * 2 + 1];                          \
    f2 k0v = {kA.x, kA.y}, k1v = {kA.z, kA.w};                            \
    f2 k2v = {kB.x, kB.y}, k3v = {kB.z, kB.w};                            \
    f2 v0v = {vA.x, vA.y}, v1v = {vA.z, vA.w};                            \
    f2 v2v = {vB.x, vB.y}, v3v = {vB.z, vB.w};                            \
    _Pragma("unroll")                                                     \
    for (int i = 0; i < NQ; i++) {                                        \
      f2 d = qr[i][0] * k0v;                                              \
      d += qr[i][1] * k1v;                                                \
      d += qr[i][2] * k2v;                                                \
      d += qr[i][3] * k3v;                                                \
      float s = d.x + d.y;                                                \
      float p = __builtin_amdgcn_exp2f(s);                                \
      if (MASKED) p = ((u) - t1 <= i) ? p : 0.f;                          \
      l4[i] += p;                                                         \
      acc[i][0] += p * v0v;                                               \
      acc[i][1] += p * v1v;                                               \
      acc[i][2] += p * v2v;                                               \
      acc[i][3] += p * v3v;                                               \
    }                                                                     \
  }

#pragma unroll 2
  for (int u = 0; u < nfull; u++) ATTN_STEP(u, false)
  for (int u = nfull; u < nend; u++) ATTN_STEP(u, true)
#undef ATTN_STEP

  long rec = (long)(bh * NCH + ch) * Tc + q0;
#pragma unroll
  for (int i = 0; i < NQ; i++) {
    if (t1 + i + 1 > 0) {
      float4* pa = (float4*)(pacc + (rec + i) * 8);
      pa[0] = make_float4(acc[i][0].x, acc[i][0].y, acc[i][1].x, acc[i][1].y);
      pa[1] = make_float4(acc[i][2].x, acc[i][2].y, acc[i][3].x, acc[i][3].y);
      pl[rec + i] = l4[i];
    }
  }
}

// ---------------------------------------------------------------------------
// 4-lane cooperative tail: reduce partials -> o ; x += o@wo^T ; x += MLP(LN2)
// Lane roles (j = lane&3):
//   A: head j&1, chunks (j>>1)::2   -> shfl_xor combine
//   B: proj outputs c = 4j..4j+3    -> shfl_xor replicate
//   C: MLP hidden units j*16..+15   -> shfl_xor combine
// LDS layouts: swo [16][17] padded, sw1 [64][17] padded, sw2 [16][64].
// ---------------------------------------------------------------------------
__device__ inline void coop_tail(
    const float* __restrict__ pacc, const float* __restrict__ pl,
    const float* swo, const float* sw1, const float* sw2,
    const float* sg2, const float* sb2, int bb, int tt, int j, float* xr) {
  // --- A: attention partial reduce
  int hh  = j & 1;
  int bh  = bb * Hc + hh;
  int nch = tt / KC + 1;
  float o8[8] = {0,0,0,0,0,0,0,0};
  float l = 0.f;
#pragma unroll 2
  for (int ch = (j >> 1); ch < nch; ch += 2) {
    long rec = (long)(bh * NCH + ch) * Tc + tt;
    const float4* pa = (const float4*)(pacc + rec * 8);
    float4 a = pa[0], b = pa[1];
    o8[0]+=a.x; o8[1]+=a.y; o8[2]+=a.z; o8[3]+=a.w;
    o8[4]+=b.x; o8[5]+=b.y; o8[6]+=b.z; o8[7]+=b.w;
    l += pl[rec];
  }
#pragma unroll
  for (int s = 0; s < 8; s++) o8[s] += shx(o8[s], 2);
  l += shx(l, 2);
  float inv = 1.f / l;
  float own[8], oth[8];
#pragma unroll
  for (int s = 0; s < 8; s++) own[s] = o8[s] * inv;
#pragma unroll
  for (int s = 0; s < 8; s++) oth[s] = shx(own[s], 1);
  float orow[Cc];
#pragma unroll
  for (int s = 0; s < 8; s++) {
    orow[s]     = (hh == 0) ? own[s] : oth[s];
    orow[8 + s] = (hh == 0) ? oth[s] : own[s];
  }
  // --- B: proj, c = 4j..4j+3
  float xc[4];
#pragma unroll
  for (int qq = 0; qq < 4; qq++) {
    int c = 4 * j + qq;
    float acc = xr[c];
#pragma unroll
    for (int kk = 0; kk < Cc; kk++) acc += orow[kk] * swo[c * 17 + kk];
    xc[qq] = acc;
  }
  {
    float p[4];
#pragma unroll
    for (int qq = 0; qq < 4; qq++) p[qq] = shx(xc[qq], 1);
    bool lo = (j & 1) == 0;
    float a8[8], b8[8];
#pragma unroll
    for (int qq = 0; qq < 4; qq++) {
      a8[qq]     = lo ? xc[qq] : p[qq];
      a8[4 + qq] = lo ? p[qq] : xc[qq];
    }
#pragma unroll
    for (int s = 0; s < 8; s++) b8[s] = shx(a8[s], 2);
    bool lo2 = (j & 2) == 0;
#pragma unroll
    for (int s = 0; s < 8; s++) {
      xr[s]     = lo2 ? a8[s] : b8[s];
      xr[8 + s] = lo2 ? b8[s] : a8[s];
    }
  }
  // --- C: MLP, hidden units j*16..j*16+15
  float h[Cc];
  layernorm16(xr, h, sg2, sb2);
  float r[Cc];
#pragma unroll
  for (int c = 0; c < Cc; c++) r[c] = 0.f;
#pragma unroll
  for (int i = 0; i < 16; i++) {
    int jj = j * 16 + i;
    float acc = 0.f;
#pragma unroll
    for (int c = 0; c < Cc; c++) acc += h[c] * sw1[jj * 17 + c];
    acc = fmaxf(acc, 0.f);
#pragma unroll
    for (int c = 0; c < Cc; c++) r[c] += acc * sw2[c * 64 + jj];
  }
#pragma unroll
  for (int c = 0; c < Cc; c++) r[c] += shx(r[c], 1);
#pragma unroll
  for (int c = 0; c < Cc; c++) r[c] += shx(r[c], 2);
#pragma unroll
  for (int c = 0; c < Cc; c++) xr[c] += r[c];
}

// ---------------------------------------------------------------------------
// K3) layer-l epilogue + layer-(l+1) LN1+QKV  (4-lane coop, 512 blocks)
// ---------------------------------------------------------------------------
__global__ __launch_bounds__(256, 4) void red_mid_kernel(
    const float* __restrict__ pacc, const float* __restrict__ pl,
    const float* __restrict__ wo, const float* __restrict__ g2,
    const float* __restrict__ b2, const float* __restrict__ w1,
    const float* __restrict__ w2,
    const float* __restrict__ wq, const float* __restrict__ wk,
    const float* __restrict__ wv, const float* __restrict__ g1,
    const float* __restrict__ b1,
    float* __restrict__ x, float* __restrict__ q, float* __restrict__ k,
    float* __restrict__ v) {
  __shared__ float swo[16 * 17], sw1[64 * 17], sw2[1024];
  __shared__ float swq[256], swk[256], swv[256];
  __shared__ float sg2[Cc], sb2[Cc], sg1[Cc], sb1[Cc];
  int tid = threadIdx.x;
  swq[tid] = wq[tid]; swk[tid] = wk[tid]; swv[tid] = wv[tid];
  { int rr = tid >> 4, c = tid & 15; swo[rr * 17 + c] = wo[tid]; }
#pragma unroll
  for (int t = tid; t < 1024; t += 256) {
    int jj = t >> 4, c = t & 15;
    sw1[jj * 17 + c] = w1[t];
    sw2[t] = w2[t];
  }
  if (tid < Cc) {
    sg2[tid] = g2[tid]; sb2[tid] = b2[tid];
    sg1[tid] = g1[tid]; sb1[tid] = b1[tid];
  }
  __syncthreads();

  int tk = blockIdx.x * 64 + (tid >> 2);
  int j  = tid & 3;
  int bb = tk >> 11, tt = tk & (Tc - 1);
  float xr[Cc];
  const float4* xp = (const float4*)(x + (long)tk * Cc);
#pragma unroll
  for (int i = 0; i < 4; i++) {
    float4 a = xp[i];
    xr[4*i]=a.x; xr[4*i+1]=a.y; xr[4*i+2]=a.z; xr[4*i+3]=a.w;
  }
  coop_tail(pacc, pl, swo, sw1, sw2, sg2, sb2, bb, tt, j, xr);
  ((float4*)(x + (long)tk * Cc))[j] =
      make_float4(xr[4*j], xr[4*j+1], xr[4*j+2], xr[4*j+3]);
  float h[Cc];
  layernorm16(xr, h, sg1, sb1);
  qkv_store_lane(h, swq, swk, swv, bb, tt, j, q, k, v);
}

// ---------------------------------------------------------------------------
// K5) final-layer epilogue + LNf + tied lm_head  (4-lane coop + head phase)
// ---------------------------------------------------------------------------
__global__ __launch_bounds__(256, 4) void red_lnf_head_kernel(
    const float* __restrict__ pacc, const float* __restrict__ pl,
    const float* __restrict__ wo, const float* __restrict__ g2,
    const float* __restrict__ b2, const float* __restrict__ w1,
    const float* __restrict__ w2, const float* __restrict__ gf,
    const float* __restrict__ bf,
    const float* __restrict__ x, const float* __restrict__ tok,
    float* __restrict__ out) {
  __shared__ float swo[16 * 17], sw1[64 * 17], sw2[1024];
  __shared__ float sg2[Cc], sb2[Cc], sgf[Cc], sbf[Cc];
  __shared__ float sh[64 * Cc];
  int tid = threadIdx.x;
  { int rr = tid >> 4, c = tid & 15; swo[rr * 17 + c] = wo[tid]; }
#pragma unroll
  for (int t = tid; t < 1024; t += 256) {
    int jj = t >> 4, c = t & 15;
    sw1[jj * 17 + c] = w1[t];
    sw2[t] = w2[t];
  }
  if (tid < Cc) {
    sg2[tid] = g2[tid]; sb2[tid] = b2[tid];
    sgf[tid] = gf[tid]; sbf[tid] = bf[tid];
  }
  __syncthreads();

  int tk = blockIdx.x * 64 + (tid >> 2);
  int j  = tid & 3;
  int bb = tk >> 11, tt = tk & (Tc - 1);
  float xr[Cc];
  const float4* xp = (const float4*)(x + (long)tk * Cc);
#pragma unroll
  for (int i = 0; i < 4; i++) {
    float4 a = xp[i];
    xr[4*i]=a.x; xr[4*i+1]=a.y; xr[4*i+2]=a.z; xr[4*i+3]=a.w;
  }
  coop_tail(pacc, pl, swo, sw1, sw2, sg2, sb2, bb, tt, j, xr);
  float h[Cc];
  layernorm16(xr, h, sgf, sbf);
  ((float4*)(sh + (tid >> 2) * Cc))[j] =
      make_float4(h[4*j], h[4*j+1], h[4*j+2], h[4*j+3]);
  __syncthreads();

  // head phase: thread = vocab id, 64 tokens from LDS (broadcast reads)
  float4 e0, e1, e2, e3;
  {
    const float4* ep = (const float4*)(tok + tid * Cc);
    e0 = ep[0]; e1 = ep[1]; e2 = ep[2]; e3 = ep[3];
  }
  int row0 = blockIdx.x * 64;
#pragma unroll 4
  for (int t = 0; t < 64; t++) {
    const float4* hp = (const float4*)(sh + t * Cc);
    float4 h0 = hp[0], h1 = hp[1], h2 = hp[2], h3 = hp[3];
    float acc = h0.x*e0.x + h0.y*e0.y + h0.z*e0.z + h0.w*e0.w
              + h1.x*e1.x + h1.y*e1.y + h1.z*e1.z + h1.w*e1.w
              + h2.x*e2.x + h2.y*e2.y + h2.z*e2.z + h2.w*e2.w
              + h3.x*e3.x + h3.y*e3.y + h3.z*e3.z + h3.w*e3.w;
    out[(long)(row0 + t) * Vc + tid] = acc;
  }
}

// ---------------------------------------------------------------------------
// launcher
// ---------------------------------------------------------------------------
extern "C" void kernel_launch(void* const* d_in, const int* in_sizes, int n_in,
                              void* d_out, int out_size, void* d_ws,
                              size_t ws_size, hipStream_t stream) {
  const int*   idx  = (const int*)  d_in[0];
  const float* tok  = (const float*)d_in[1];
  const float* pos  = (const float*)d_in[2];
  const float* wq   = (const float*)d_in[3];
  const float* wk   = (const float*)d_in[4];
  const float* wv   = (const float*)d_in[5];
  const float* wo   = (const float*)d_in[6];
  const float* ln1g = (const float*)d_in[7];
  const float* ln1b = (const float*)d_in[8];
  const float* ln2g = (const float*)d_in[9];
  const float* ln2b = (const float*)d_in[10];
  const float* w1   = (const float*)d_in[11];
  const float* w2   = (const float*)d_in[12];
  const float* lnfg = (const float*)d_in[13];
  const float* lnfb = (const float*)d_in[14];
  float* out = (float*)d_out;

  // workspace layout (floats):
  // x: 2MB | q,k,v: 2MB each | pacc: 32MB | pl: 4MB
  float* x    = (float*)d_ws;
  float* q    = x + (long)BT * Cc;
  float* k    = q + (long)Bc * Hc * Tc * HSc;
  float* v    = k + (long)Bc * Hc * Tc * HSc;
  float* pacc = v + (long)Bc * Hc * Tc * HSc;
  float* pl   = pacc + (long)Bc * Hc * NCH * Tc * HSc;

  dim3 agrid(NIT * Bc * Hc);   // 768 blocks, item-major (largest first)

  embed_ln_qkv_kernel<<<BT / 64, 256, 0, stream>>>(
      idx, tok, pos, wq, wk, wv, ln1g, ln1b, x, q, k, v);
  attn_kernel<<<agrid, 256, 0, stream>>>(q, k, v, pacc, pl);
  red_mid_kernel<<<BT / 64, 256, 0, stream>>>(
      pacc, pl, wo, ln2g, ln2b, w1, w2,
      wq + Hc * Cc * HSc, wk + Hc * Cc * HSc, wv + Hc * Cc * HSc,
      ln1g + Cc, ln1b + Cc, x, q, k, v);
  attn_kernel<<<agrid, 256, 0, stream>>>(q, k, v, pacc, pl);
  red_lnf_head_kernel<<<BT / 64, 256, 0, stream>>>(
      pacc, pl, wo + Cc * Cc, ln2g + Cc, ln2b + Cc,
      w1 + 4 * Cc * Cc, w2 + 4 * Cc * Cc, lnfg, lnfb, x, tok, out);
}

// Round 5
// 230.798 us; speedup vs baseline: 1.3157x; 1.0153x over previous
//
#include <hip/hip_runtime.h>
#include <math.h>

// Problem constants (MicroGPT)
constexpr int Bc  = 16;
constexpr int Tc  = 2048;
constexpr int Cc  = 16;
constexpr int Hc  = 2;
constexpr int HSc = 8;
constexpr int Lc  = 2;
constexpr int Vc  = 256;
constexpr int BT  = Bc * Tc;          // 32768 tokens
constexpr float EPSc = 1e-5f;

// Attention: WAVE-GRANULAR equal tasks. task=(bh, qq<8, ch<=2qq+1): every
// task is exactly 128 key-steps (nend==128 for all valid tasks). 2304 tasks
// = 9 single-wave blocks per CU, ALL co-resident (72KB LDS, ~90 VGPR) ->
// 2.25 waves/SIMD everywhere, no tail, no dispatch-order assumptions.
// (R0/R1/R4 all ~54us with VALUBusy pinned 43% despite 4x different LDS
// instr counts -> limiter was ~1.3 waves/SIMD avg issue efficiency, not a
// pipe. 4-wave blocks had idle waves + uneven residency.)
constexpr int KC  = 128;              // keys per chunk (LDS tile)
constexpr int NCH = Tc / KC;          // 16 chunks (pacc layout - do not change)
constexpr int NQ  = 4;                // queries per thread (amortize LDS reads)
constexpr int NTASK = 72;             // tasks per (b,h): sum_{qq<8}(2qq+2)

typedef float f2 __attribute__((ext_vector_type(2)));
typedef float f4 __attribute__((ext_vector_type(4)));

__device__ inline float shx(float v, int m) { return __shfl_xor(v, m, 64); }

// ---------------------------------------------------------------------------
// LN helper
// ---------------------------------------------------------------------------
__device__ inline void layernorm16(const float* xr, float* h,
                                   const float* g, const float* b) {
  float m = 0.f;
#pragma unroll
  for (int c = 0; c < Cc; c++) m += xr[c];
  m *= (1.f / Cc);
  float var = 0.f;
#pragma unroll
  for (int c = 0; c < Cc; c++) { float d = xr[c] - m; var += d * d; }
  var *= (1.f / Cc);
  float rs = rsqrtf(var + EPSc);
#pragma unroll
  for (int c = 0; c < Cc; c++) h[c] = (xr[c] - m) * rs * g[c] + b[c];
}

// ---------------------------------------------------------------------------
// 4-lane-coop QKV: lane j computes s={2j,2j+1} of every (head, q/k/v) vector
// ---------------------------------------------------------------------------
__device__ inline void qkv_store_lane(const float* h, const float* swq,
                                      const float* swk, const float* swv,
                                      int bb, int tt, int j,
                                      float* __restrict__ q,
                                      float* __restrict__ k,
                                      float* __restrict__ v) {
#pragma unroll
  for (int hh = 0; hh < Hc; hh++) {
    float q0 = 0.f, q1 = 0.f, k0 = 0.f, k1 = 0.f, v0 = 0.f, v1 = 0.f;
#pragma unroll
    for (int c = 0; c < Cc; c++) {
      float hv = h[c];
      const float* wqp = swq + (hh * Cc + c) * HSc + 2 * j;
      const float* wkp = swk + (hh * Cc + c) * HSc + 2 * j;
      const float* wvp = swv + (hh * Cc + c) * HSc + 2 * j;
      q0 += hv * wqp[0]; q1 += hv * wqp[1];
      k0 += hv * wkp[0]; k1 += hv * wkp[1];
      v0 += hv * wvp[0]; v1 += hv * wvp[1];
    }
    long base = ((long)(bb * Hc + hh) * Tc + tt) * HSc;
    ((float2*)(q + base))[j] = make_float2(q0, q1);
    ((float2*)(k + base))[j] = make_float2(k0, k1);
    ((float2*)(v + base))[j] = make_float2(v0, v1);
  }
}

// ---------------------------------------------------------------------------
// K1) x = tok_emb[idx] + pos_emb ; h = LN1(x) ; q,k,v = h @ W  (layer 0)
// ---------------------------------------------------------------------------
__global__ __launch_bounds__(256, 4) void embed_ln_qkv_kernel(
    const int* __restrict__ idx, const float* __restrict__ tok,
    const float* __restrict__ pos,
    const float* __restrict__ wq, const float* __restrict__ wk,
    const float* __restrict__ wv,
    const float* __restrict__ g, const float* __restrict__ b,
    float* __restrict__ x, float* __restrict__ q, float* __restrict__ k,
    float* __restrict__ v) {
  __shared__ float swq[256], swk[256], swv[256], sg[Cc], sb[Cc];
  int tid = threadIdx.x;
  swq[tid] = wq[tid];
  swk[tid] = wk[tid];
  swv[tid] = wv[tid];
  if (tid < Cc) { sg[tid] = g[tid]; sb[tid] = b[tid]; }
  __syncthreads();

  int tk = blockIdx.x * 64 + (tid >> 2);
  int j  = tid & 3;
  int tt = tk & (Tc - 1);
  int bb = tk >> 11;
  int id = idx[tk];
  float xr[Cc];
  const float4* te = (const float4*)(tok + id * Cc);
  const float4* pe = (const float4*)(pos + tt * Cc);
#pragma unroll
  for (int i = 0; i < 4; i++) {
    float4 a = te[i], p = pe[i];
    xr[4*i] = a.x + p.x; xr[4*i+1] = a.y + p.y;
    xr[4*i+2] = a.z + p.z; xr[4*i+3] = a.w + p.w;
  }
  ((float4*)(x + (long)tk * Cc))[j] =
      make_float4(xr[4*j], xr[4*j+1], xr[4*j+2], xr[4*j+3]);
  float h[Cc];
  layernorm16(xr, h, sg, sb);
  qkv_store_lane(h, swq, swk, swv, bb, tt, j, q, k, v);
}

// ---------------------------------------------------------------------------
// K2) Causal flash attention, wave-granular. One 64-thread block = one wave
//     = one task (bh, qq, ch): queries qq*256..+255 (4/thread) vs chunk ch.
//     Exactly 128 key-steps per task. Wave stages its own K/V tile in LDS
//     (f4 reads), f2/pk-FMA math, wave-uniform bounds, masked epilogue.
//     Writes UNNORMALIZED partials (acc[8], l) per (query, chunk).
// ---------------------------------------------------------------------------
__global__ __launch_bounds__(64, 3) void attn_kernel(
    const float* __restrict__ q, const float* __restrict__ k,
    const float* __restrict__ v, float* __restrict__ pacc,
    float* __restrict__ pl) {
  int t  = blockIdx.x >> 5;       // 0..71 task index within (b,h)
  int bh = blockIdx.x & 31;       // 0..31
  // invert t -> (qq, ch): prefix(qq) = qq*(qq+1), ch = t - prefix, ch<=2qq+1
  int qq = (int)((sqrtf(4.f * (float)t + 1.f) - 1.f) * 0.5f);
  while ((qq + 1) * (qq + 2) <= t) qq++;
  while (qq * (qq + 1) > t) qq--;
  int ch = t - qq * (qq + 1);
  int k0 = ch * KC;

  __shared__ float sk[KC * HSc], sv[KC * HSc];
  int tid = threadIdx.x;          // 0..63 == lane
  {
    const float4* ksrc = (const float4*)(k + ((long)bh * Tc + k0) * HSc);
    const float4* vsrc = (const float4*)(v + ((long)bh * Tc + k0) * HSc);
    float4* skw = (float4*)sk;
    float4* svw = (float4*)sv;
#pragma unroll
    for (int r = 0; r < 4; r++) {          // KC*HSc/4 = 256 float4, 64 lanes
      skw[r * 64 + tid] = ksrc[r * 64 + tid];
      svw[r * 64 + tid] = vsrc[r * 64 + tid];
    }
  }
  __syncthreads();                // 1-wave block: compiles to waitcnt

  int q0 = qq * 256 + NQ * tid;   // 4 consecutive queries q0..q0+3
  int t1 = q0 - k0;               // key u unmasked for ALL 4 iff u<=t1

  // wave-uniform bounds (lane 0 has the smallest q0 in the wave)
  int t1f   = qq * 256 - k0;      // == readfirstlane(t1), computed uniformly
  int nfull = t1f + 1;            // u < nfull: unmasked for every lane/query
  if (nfull < 0) nfull = 0;
  if (nfull > KC) nfull = KC;
  int nend  = t1f + 64 * NQ;      // == 128 for every valid task
  if (nend > KC) nend = KC;

  const float pre = 0.35355339059327373f * 1.4426950408889634f;
  f2 qr[NQ][4];
  f2 acc[NQ][4];
  float l4[NQ];
  {
    const f2* qp = (const f2*)(q + ((long)bh * Tc + q0) * HSc);
#pragma unroll
    for (int i = 0; i < NQ; i++) {
#pragma unroll
      for (int jj = 0; jj < 4; jj++) {
        qr[i][jj] = qp[i * 4 + jj] * pre;
        acc[i][jj] = {0.f, 0.f};
      }
      l4[i] = 0.f;
    }
  }

  const f4* skp = (const f4*)sk;
  const f4* svp = (const f4*)sv;

#define ATTN_STEP(u, MASKED)                                              \
  {                                                                       \
    f4 kA = skp[(u) * 2], kB = skp[(u) * 2 + 1];                          \
    f4 vA = svp[(u) * 2], vB = svp[(u) * 2 + 1];                          \
    f2 k0v = {kA.x, kA.y}, k1v = {kA.z, kA.w};                            \
    f2 k2v = {kB.x, kB.y}, k3v = {kB.z, kB.w};                            \
    f2 v0v = {vA.x, vA.y}, v1v = {vA.z, vA.w};                            \
    f2 v2v = {vB.x, vB.y}, v3v = {vB.z, vB.w};                            \
    _Pragma("unroll")                                                     \
    for (int i = 0; i < NQ; i++) {                                        \
      f2 d = qr[i][0] * k0v;                                              \
      d += qr[i][1] * k1v;                                                \
      d += qr[i][2] * k2v;                                                \
      d += qr[i][3] * k3v;                                                \
      float s = d.x + d.y;                                                \
      float p = __builtin_amdgcn_exp2f(s);                                \
      if (MASKED) p = ((u) - t1 <= i) ? p : 0.f;                          \
      l4[i] += p;                                                         \
      acc[i][0] += p * v0v;                                               \
      acc[i][1] += p * v1v;                                               \
      acc[i][2] += p * v2v;                                               \
      acc[i][3] += p * v3v;                                               \
    }                                                                     \
  }

#pragma unroll 2
  for (int u = 0; u < nfull; u++) ATTN_STEP(u, false)
  for (int u = nfull; u < nend; u++) ATTN_STEP(u, true)
#undef ATTN_STEP

  long rec = (long)(bh * NCH + ch) * Tc + q0;
#pragma unroll
  for (int i = 0; i < NQ; i++) {
    if (t1 + i + 1 > 0) {
      float4* pa = (float4*)(pacc + (rec + i) * 8);
      pa[0] = make_float4(acc[i][0].x, acc[i][0].y, acc[i][1].x, acc[i][1].y);
      pa[1] = make_float4(acc[i][2].x, acc[i][2].y, acc[i][3].x, acc[i][3].y);
      pl[rec + i] = l4[i];
    }
  }
}

// ---------------------------------------------------------------------------
// 4-lane cooperative tail: reduce partials -> o ; x += o@wo^T ; x += MLP(LN2)
// Lane roles (j = lane&3):
//   A: head j&1, chunks (j>>1)::2   -> shfl_xor combine
//   B: proj outputs c = 4j..4j+3    -> shfl_xor replicate
//   C: MLP hidden units j*16..+15   -> shfl_xor combine
// LDS layouts: swo [16][17] padded, sw1 [64][17] padded, sw2 [16][64].
// ---------------------------------------------------------------------------
__device__ inline void coop_tail(
    const float* __restrict__ pacc, const float* __restrict__ pl,
    const float* swo, const float* sw1, const float* sw2,
    const float* sg2, const float* sb2, int bb, int tt, int j, float* xr) {
  // --- A: attention partial reduce
  int hh  = j & 1;
  int bh  = bb * Hc + hh;
  int nch = tt / KC + 1;
  float o8[8] = {0,0,0,0,0,0,0,0};
  float l = 0.f;
#pragma unroll 2
  for (int ch = (j >> 1); ch < nch; ch += 2) {
    long rec = (long)(bh * NCH + ch) * Tc + tt;
    const float4* pa = (const float4*)(pacc + rec * 8);
    float4 a = pa[0], b = pa[1];
    o8[0]+=a.x; o8[1]+=a.y; o8[2]+=a.z; o8[3]+=a.w;
    o8[4]+=b.x; o8[5]+=b.y; o8[6]+=b.z; o8[7]+=b.w;
    l += pl[rec];
  }
#pragma unroll
  for (int s = 0; s < 8; s++) o8[s] += shx(o8[s], 2);
  l += shx(l, 2);
  float inv = 1.f / l;
  float own[8], oth[8];
#pragma unroll
  for (int s = 0; s < 8; s++) own[s] = o8[s] * inv;
#pragma unroll
  for (int s = 0; s < 8; s++) oth[s] = shx(own[s], 1);
  float orow[Cc];
#pragma unroll
  for (int s = 0; s < 8; s++) {
    orow[s]     = (hh == 0) ? own[s] : oth[s];
    orow[8 + s] = (hh == 0) ? oth[s] : own[s];
  }
  // --- B: proj, c = 4j..4j+3
  float xc[4];
#pragma unroll
  for (int qq = 0; qq < 4; qq++) {
    int c = 4 * j + qq;
    float acc = xr[c];
#pragma unroll
    for (int kk = 0; kk < Cc; kk++) acc += orow[kk] * swo[c * 17 + kk];
    xc[qq] = acc;
  }
  {
    float p[4];
#pragma unroll
    for (int qq = 0; qq < 4; qq++) p[qq] = shx(xc[qq], 1);
    bool lo = (j & 1) == 0;
    float a8[8], b8[8];
#pragma unroll
    for (int qq = 0; qq < 4; qq++) {
      a8[qq]     = lo ? xc[qq] : p[qq];
      a8[4 + qq] = lo ? p[qq] : xc[qq];
    }
#pragma unroll
    for (int s = 0; s < 8; s++) b8[s] = shx(a8[s], 2);
    bool lo2 = (j & 2) == 0;
#pragma unroll
    for (int s = 0; s < 8; s++) {
      xr[s]     = lo2 ? a8[s] : b8[s];
      xr[8 + s] = lo2 ? b8[s] : a8[s];
    }
  }
  // --- C: MLP, hidden units j*16..j*16+15
  float h[Cc];
  layernorm16(xr, h, sg2, sb2);
  float r[Cc];
#pragma unroll
  for (int c = 0; c < Cc; c++) r[c] = 0.f;
#pragma unroll
  for (int i = 0; i < 16; i++) {
    int jj = j * 16 + i;
    float acc = 0.f;
#pragma unroll
    for (int c = 0; c < Cc; c++) acc += h[c] * sw1[jj * 17 + c];
    acc = fmaxf(acc, 0.f);
#pragma unroll
    for (int c = 0; c < Cc; c++) r[c] += acc * sw2[c * 64 + jj];
  }
#pragma unroll
  for (int c = 0; c < Cc; c++) r[c] += shx(r[c], 1);
#pragma unroll
  for (int c = 0; c < Cc; c++) r[c] += shx(r[c], 2);
#pragma unroll
  for (int c = 0; c < Cc; c++) xr[c] += r[c];
}

// ---------------------------------------------------------------------------
// K3) layer-l epilogue + layer-(l+1) LN1+QKV  (4-lane coop, 512 blocks)
// ---------------------------------------------------------------------------
__global__ __launch_bounds__(256, 4) void red_mid_kernel(
    const float* __restrict__ pacc, const float* __restrict__ pl,
    const float* __restrict__ wo, const float* __restrict__ g2,
    const float* __restrict__ b2, const float* __restrict__ w1,
    const float* __restrict__ w2,
    const float* __restrict__ wq, const float* __restrict__ wk,
    const float* __restrict__ wv, const float* __restrict__ g1,
    const float* __restrict__ b1,
    float* __restrict__ x, float* __restrict__ q, float* __restrict__ k,
    float* __restrict__ v) {
  __shared__ float swo[16 * 17], sw1[64 * 17], sw2[1024];
  __shared__ float swq[256], swk[256], swv[256];
  __shared__ float sg2[Cc], sb2[Cc], sg1[Cc], sb1[Cc];
  int tid = threadIdx.x;
  swq[tid] = wq[tid]; swk[tid] = wk[tid]; swv[tid] = wv[tid];
  { int rr = tid >> 4, c = tid & 15; swo[rr * 17 + c] = wo[tid]; }
#pragma unroll
  for (int t = tid; t < 1024; t += 256) {
    int jj = t >> 4, c = t & 15;
    sw1[jj * 17 + c] = w1[t];
    sw2[t] = w2[t];
  }
  if (tid < Cc) {
    sg2[tid] = g2[tid]; sb2[tid] = b2[tid];
    sg1[tid] = g1[tid]; sb1[tid] = b1[tid];
  }
  __syncthreads();

  int tk = blockIdx.x * 64 + (tid >> 2);
  int j  = tid & 3;
  int bb = tk >> 11, tt = tk & (Tc - 1);
  float xr[Cc];
  const float4* xp = (const float4*)(x + (long)tk * Cc);
#pragma unroll
  for (int i = 0; i < 4; i++) {
    float4 a = xp[i];
    xr[4*i]=a.x; xr[4*i+1]=a.y; xr[4*i+2]=a.z; xr[4*i+3]=a.w;
  }
  coop_tail(pacc, pl, swo, sw1, sw2, sg2, sb2, bb, tt, j, xr);
  ((float4*)(x + (long)tk * Cc))[j] =
      make_float4(xr[4*j], xr[4*j+1], xr[4*j+2], xr[4*j+3]);
  float h[Cc];
  layernorm16(xr, h, sg1, sb1);
  qkv_store_lane(h, swq, swk, swv, bb, tt, j, q, k, v);
}

// ---------------------------------------------------------------------------
// K5) final-layer epilogue + LNf + tied lm_head  (4-lane coop + head phase)
// ---------------------------------------------------------------------------
__global__ __launch_bounds__(256, 4) void red_lnf_head_kernel(
    const float* __restrict__ pacc, const float* __restrict__ pl,
    const float* __restrict__ wo, const float* __restrict__ g2,
    const float* __restrict__ b2, const float* __restrict__ w1,
    const float* __restrict__ w2, const float* __restrict__ gf,
    const float* __restrict__ bf,
    const float* __restrict__ x, const float* __restrict__ tok,
    float* __restrict__ out) {
  __shared__ float swo[16 * 17], sw1[64 * 17], sw2[1024];
  __shared__ float sg2[Cc], sb2[Cc], sgf[Cc], sbf[Cc];
  __shared__ float sh[64 * Cc];
  int tid = threadIdx.x;
  { int rr = tid >> 4, c = tid & 15; swo[rr * 17 + c] = wo[tid]; }
#pragma unroll
  for (int t = tid; t < 1024; t += 256) {
    int jj = t >> 4, c = t & 15;
    sw1[jj * 17 + c] = w1[t];
    sw2[t] = w2[t];
  }
  if (tid < Cc) {
    sg2[tid] = g2[tid]; sb2[tid] = b2[tid];
    sgf[tid] = gf[tid]; sbf[tid] = bf[tid];
  }
  __syncthreads();

  int tk = blockIdx.x * 64 + (tid >> 2);
  int j  = tid & 3;
  int bb = tk >> 11, tt = tk & (Tc - 1);
  float xr[Cc];
  const float4* xp = (const float4*)(x + (long)tk * Cc);
#pragma unroll
  for (int i = 0; i < 4; i++) {
    float4 a = xp[i];
    xr[4*i]=a.x; xr[4*i+1]=a.y; xr[4*i+2]=a.z; xr[4*i+3]=a.w;
  }
  coop_tail(pacc, pl, swo, sw1, sw2, sg2, sb2, bb, tt, j, xr);
  float h[Cc];
  layernorm16(xr, h, sgf, sbf);
  ((float4*)(sh + (tid >> 2) * Cc))[j] =
      make_float4(h[4*j], h[4*j+1], h[4*j+2], h[4*j+3]);
  __syncthreads();

  // head phase: thread = vocab id, 64 tokens from LDS (broadcast reads)
  float4 e0, e1, e2, e3;
  {
    const float4* ep = (const float4*)(tok + tid * Cc);
    e0 = ep[0]; e1 = ep[1]; e2 = ep[2]; e3 = ep[3];
  }
  int row0 = blockIdx.x * 64;
#pragma unroll 4
  for (int t = 0; t < 64; t++) {
    const float4* hp = (const float4*)(sh + t * Cc);
    float4 h0 = hp[0], h1 = hp[1], h2 = hp[2], h3 = hp[3];
    float acc = h0.x*e0.x + h0.y*e0.y + h0.z*e0.z + h0.w*e0.w
              + h1.x*e1.x + h1.y*e1.y + h1.z*e1.z + h1.w*e1.w
              + h2.x*e2.x + h2.y*e2.y + h2.z*e2.z + h2.w*e2.w
              + h3.x*e3.x + h3.y*e3.y + h3.z*e3.z + h3.w*e3.w;
    out[(long)(row0 + t) * Vc + tid] = acc;
  }
}

// ---------------------------------------------------------------------------
// launcher
// ---------------------------------------------------------------------------
extern "C" void kernel_launch(void* const* d_in, const int* in_sizes, int n_in,
                              void* d_out, int out_size, void* d_ws,
                              size_t ws_size, hipStream_t stream) {
  const int*   idx  = (const int*)  d_in[0];
  const float* tok  = (const float*)d_in[1];
  const float* pos  = (const float*)d_in[2];
  const float* wq   = (const float*)d_in[3];
  const float* wk   = (const float*)d_in[4];
  const float* wv   = (const float*)d_in[5];
  const float* wo   = (const float*)d_in[6];
  const float* ln1g = (const float*)d_in[7];
  const float* ln1b = (const float*)d_in[8];
  const float* ln2g = (const float*)d_in[9];
  const float* ln2b = (const float*)d_in[10];
  const float* w1   = (const float*)d_in[11];
  const float* w2   = (const float*)d_in[12];
  const float* lnfg = (const float*)d_in[13];
  const float* lnfb = (const float*)d_in[14];
  float* out = (float*)d_out;

  // workspace layout (floats):
  // x: 2MB | q,k,v: 2MB each | pacc: 32MB | pl: 4MB
  float* x    = (float*)d_ws;
  float* q    = x + (long)BT * Cc;
  float* k    = q + (long)Bc * Hc * Tc * HSc;
  float* v    = k + (long)Bc * Hc * Tc * HSc;
  float* pacc = v + (long)Bc * Hc * Tc * HSc;
  float* pl   = pacc + (long)Bc * Hc * NCH * Tc * HSc;

  dim3 agrid(NTASK * Bc * Hc);   // 2304 single-wave blocks, all co-resident

  embed_ln_qkv_kernel<<<BT / 64, 256, 0, stream>>>(
      idx, tok, pos, wq, wk, wv, ln1g, ln1b, x, q, k, v);
  attn_kernel<<<agrid, 64, 0, stream>>>(q, k, v, pacc, pl);
  red_mid_kernel<<<BT / 64, 256, 0, stream>>>(
      pacc, pl, wo, ln2g, ln2b, w1, w2,
      wq + Hc * Cc * HSc, wk + Hc * Cc * HSc, wv + Hc * Cc * HSc,
      ln1g + Cc, ln1b + Cc, x, q, k, v);
  attn_kernel<<<agrid, 64, 0, stream>>>(q, k, v, pacc, pl);
  red_lnf_head_kernel<<<BT / 64, 256, 0, stream>>>(
      pacc, pl, wo + Cc * Cc, ln2g + Cc, ln2b + Cc,
      w1 + 4 * Cc * Cc, w2 + 4 * Cc * Cc, lnfg, lnfb, x, tok, out);
}

// Round 6
// 171.610 us; speedup vs baseline: 1.7695x; 1.3449x over previous
//
#include <hip/hip_runtime.h>
#include <math.h>

// Problem constants (MicroGPT)
constexpr int Bc  = 16;
constexpr int Tc  = 2048;
constexpr int Cc  = 16;
constexpr int Hc  = 2;
constexpr int HSc = 8;
constexpr int Vc  = 256;
constexpr int BT  = Bc * Tc;          // 32768 tokens
constexpr float EPSc = 1e-5f;

// R0-R5 lesson: fp32 VALU attention is pinned at ~55us/dispatch (VALUBusy 43%,
// MfmaUtil 0) under 5 different schedules. The fix is the matrix pipe:
// bf16 MFMA attention (16x16x32), swapped-QK so P feeds PV in-lane via a
// V-permutation pi(16t+4G+r)=8G+4t+r applied at V-write time. pacc/pl
// partial-reduction (40MB/layer HBM round trip) eliminated: waves own full
// query rows and write normalized O directly.

typedef short s8v __attribute__((ext_vector_type(8)));  // 8 bf16 (A/B frag)
typedef float f4v __attribute__((ext_vector_type(4)));  // 4 f32  (C/D frag)

__device__ inline float shx(float v, int m) { return __shfl_xor(v, m, 64); }

__device__ inline unsigned short f2bf(float f) {        // f32 -> bf16 RNE
  union { float f; unsigned u; } c; c.f = f;
  unsigned u = c.u + 0x7fffu + ((c.u >> 16) & 1u);
  return (unsigned short)(u >> 16);
}

__device__ inline unsigned cvtpk(float a, float b) {    // pack 2 f32 -> 2 bf16
  unsigned r;
  asm("v_cvt_pk_bf16_f32 %0, %1, %2" : "=v"(r) : "v"(a), "v"(b));
  return r;
}

// ---------------------------------------------------------------------------
// LN helper
// ---------------------------------------------------------------------------
__device__ inline void layernorm16(const float* xr, float* h,
                                   const float* g, const float* b) {
  float m = 0.f;
#pragma unroll
  for (int c = 0; c < Cc; c++) m += xr[c];
  m *= (1.f / Cc);
  float var = 0.f;
#pragma unroll
  for (int c = 0; c < Cc; c++) { float d = xr[c] - m; var += d * d; }
  var *= (1.f / Cc);
  float rs = rsqrtf(var + EPSc);
#pragma unroll
  for (int c = 0; c < Cc; c++) h[c] = (xr[c] - m) * rs * g[c] + b[c];
}

// ---------------------------------------------------------------------------
// 4-lane-coop QKV -> bf16 outputs. Lane j computes s={2j,2j+1}.
// qb: [bh][T][8] bf16, Q pre-scaled by HS^-0.5*log2(e).
// kb: [bh][T][8] bf16.
// vt: [bh][8][T] bf16, column index PERMUTED within each 32-key block:
//     actual key a (local=a&31, t=local>>4, G=(local&15)>>2, r=local&3)
//     stored at pv-local = 8G+4t+r, so QK's D-layout feeds PV's A-frag
//     in-lane with zero shuffles.
// ---------------------------------------------------------------------------
__device__ inline void qkv_store_bf16(const float* h, const float* swq,
                                      const float* swk, const float* swv,
                                      int bb, int tt, int j,
                                      unsigned short* __restrict__ qb,
                                      unsigned short* __restrict__ kb,
                                      unsigned short* __restrict__ vt) {
  const float pre = 0.35355339059327373f * 1.4426950408889634f;
  int a = tt & 31;
  int pvpos = (tt & ~31) | ((((a & 15) >> 2)) << 3) | (((a >> 4) & 1) << 2) |
              (a & 3);
#pragma unroll
  for (int hh = 0; hh < Hc; hh++) {
    float q0 = 0.f, q1 = 0.f, k0 = 0.f, k1 = 0.f, v0 = 0.f, v1 = 0.f;
#pragma unroll
    for (int c = 0; c < Cc; c++) {
      float hv = h[c];
      const float* wqp = swq + (hh * Cc + c) * HSc + 2 * j;
      const float* wkp = swk + (hh * Cc + c) * HSc + 2 * j;
      const float* wvp = swv + (hh * Cc + c) * HSc + 2 * j;
      q0 += hv * wqp[0]; q1 += hv * wqp[1];
      k0 += hv * wkp[0]; k1 += hv * wkp[1];
      v0 += hv * wvp[0]; v1 += hv * wvp[1];
    }
    int bh = bb * Hc + hh;
    long rowb = ((long)bh * Tc + tt) * 8 + 2 * j;
    unsigned qp = (unsigned)f2bf(q0 * pre) | ((unsigned)f2bf(q1 * pre) << 16);
    unsigned kp = (unsigned)f2bf(k0) | ((unsigned)f2bf(k1) << 16);
    *(unsigned*)(qb + rowb) = qp;
    *(unsigned*)(kb + rowb) = kp;
    vt[((long)bh * 8 + 2 * j) * Tc + pvpos]     = f2bf(v0);
    vt[((long)bh * 8 + 2 * j + 1) * Tc + pvpos] = f2bf(v1);
  }
}

// ---------------------------------------------------------------------------
// K1) x = tok_emb[idx] + pos_emb ; h = LN1(x) ; qkv -> bf16 buffers.
//     Block 0 also zeroes the 64B pad region used for MFMA operand padding.
// ---------------------------------------------------------------------------
__global__ __launch_bounds__(256, 4) void embed_ln_qkv_kernel(
    const int* __restrict__ idx, const float* __restrict__ tok,
    const float* __restrict__ pos,
    const float* __restrict__ wq, const float* __restrict__ wk,
    const float* __restrict__ wv,
    const float* __restrict__ g, const float* __restrict__ b,
    float* __restrict__ x, unsigned short* __restrict__ qb,
    unsigned short* __restrict__ kb, unsigned short* __restrict__ vt,
    unsigned short* __restrict__ zp) {
  __shared__ float swq[256], swk[256], swv[256], sg[Cc], sb[Cc];
  int tid = threadIdx.x;
  if (blockIdx.x == 0 && tid < 16) ((unsigned*)zp)[tid] = 0u;  // 64B zeros
  swq[tid] = wq[tid];
  swk[tid] = wk[tid];
  swv[tid] = wv[tid];
  if (tid < Cc) { sg[tid] = g[tid]; sb[tid] = b[tid]; }
  __syncthreads();

  int tk = blockIdx.x * 64 + (tid >> 2);
  int j  = tid & 3;
  int tt = tk & (Tc - 1);
  int bb = tk >> 11;
  int id = idx[tk];
  float xr[Cc];
  const float4* te = (const float4*)(tok + id * Cc);
  const float4* pe = (const float4*)(pos + tt * Cc);
#pragma unroll
  for (int i = 0; i < 4; i++) {
    float4 a = te[i], p = pe[i];
    xr[4*i] = a.x + p.x; xr[4*i+1] = a.y + p.y;
    xr[4*i+2] = a.z + p.z; xr[4*i+3] = a.w + p.w;
  }
  ((float4*)(x + (long)tk * Cc))[j] =
      make_float4(xr[4*j], xr[4*j+1], xr[4*j+2], xr[4*j+3]);
  float h[Cc];
  layernorm16(xr, h, sg, sb);
  qkv_store_bf16(h, swq, swk, swv, bb, tt, j, qb, kb, vt);
}

// ---------------------------------------------------------------------------
// K2) MFMA causal flash attention. One wave (64-thr block) owns TWO q-tiles
//     (qt, 127-qt) -> every wave does exactly 65+1 32-key blocks: perfectly
//     balanced. Per 32 keys: 2 QK MFMA (swapped: D=S^T, lane l holds P for
//     query l&15) + exp2 + cvt_pk + 1 PV MFMA (in-lane P thanks to the V
//     permutation). Unnormalized exp2, diagonal masked only in last block.
//     Writes normalized O[bh][T][8] f32 directly (no partials).
// ---------------------------------------------------------------------------
__global__ __launch_bounds__(64, 4) void attn_kernel(
    const unsigned short* __restrict__ qb,
    const unsigned short* __restrict__ kb,
    const unsigned short* __restrict__ vt,
    const unsigned short* __restrict__ zp,
    float* __restrict__ o) {
  int pairId = blockIdx.x >> 5;     // 0..63
  int bh     = blockIdx.x & 31;
  int lane   = threadIdx.x;
  int lq     = lane & 15;
  int g4     = (lane >> 4) << 2;    // 4*(lane>>4)
  bool real16 = lane < 16;
  bool real8  = lq < 8;
  bool md[4];                       // diagonal mask: key-in-tile <= q-in-tile
#pragma unroll
  for (int r = 0; r < 4; r++) md[r] = (g4 + r) <= lq;

  const f4v zf = {0.f, 0.f, 0.f, 0.f};

#pragma unroll 1
  for (int hf = 0; hf < 2; hf++) {
    int qt = hf ? (127 - pairId) : pairId;
    int q0 = qt << 4;
    int NB = (qt + 2) >> 1;         // 32-key blocks; last contains diagonal

    // Q fragment (B-operand): lanes<16 load full bf16 row, others zeros.
    s8v qf = *(real16 ? (const s8v*)(qb + ((long)bh * Tc + q0 + lq) * 8)
                      : (const s8v*)zp);
    // K pointers (A-operand rows), zero-lanes pinned to pad (step 0).
    const unsigned short* kp_ = real16 ? kb + ((long)bh * Tc + lq) * 8
                                       : zp;
    long kts = real16 ? 128 : 0;    // ushorts per 16-key tile
    // V pointer (B-operand), d-row lq<8, k-block offset by lane group.
    const unsigned short* vp_ =
        real8 ? vt + ((long)bh * 8 + lq) * Tc + (g4 << 1) : zp;
    long vts = real8 ? 32 : 0;      // ushorts per 32-key block

    f4v oacc = zf;
    float lsum = 0.f;

    s8v kf0 = *(const s8v*)kp_;
    s8v kf1 = *(const s8v*)(kp_ + kts);
    kp_ += 2 * kts;
    s8v vf = *(const s8v*)vp_;
    vp_ += vts;

    for (int b = 0; b < NB - 1; b++) {
      s8v kn0 = *(const s8v*)kp_;
      s8v kn1 = *(const s8v*)(kp_ + kts);
      kp_ += 2 * kts;
      s8v vn = *(const s8v*)vp_;
      vp_ += vts;

      f4v st0 = __builtin_amdgcn_mfma_f32_16x16x32_bf16(kf0, qf, zf, 0, 0, 0);
      f4v st1 = __builtin_amdgcn_mfma_f32_16x16x32_bf16(kf1, qf, zf, 0, 0, 0);
      float p00 = __builtin_amdgcn_exp2f(st0[0]);
      float p01 = __builtin_amdgcn_exp2f(st0[1]);
      float p02 = __builtin_amdgcn_exp2f(st0[2]);
      float p03 = __builtin_amdgcn_exp2f(st0[3]);
      float p10 = __builtin_amdgcn_exp2f(st1[0]);
      float p11 = __builtin_amdgcn_exp2f(st1[1]);
      float p12 = __builtin_amdgcn_exp2f(st1[2]);
      float p13 = __builtin_amdgcn_exp2f(st1[3]);
      lsum += ((p00 + p01) + (p02 + p03)) + ((p10 + p11) + (p12 + p13));
      union { unsigned u[4]; s8v s; } pu;
      pu.u[0] = cvtpk(p00, p01);
      pu.u[1] = cvtpk(p02, p03);
      pu.u[2] = cvtpk(p10, p11);
      pu.u[3] = cvtpk(p12, p13);
      oacc = __builtin_amdgcn_mfma_f32_16x16x32_bf16(pu.s, vf, oacc, 0, 0, 0);
      kf0 = kn0; kf1 = kn1; vf = vn;
    }

    // last block: tile (qt&1 ? qt-1 : qt) in slot0, diagonal masking
    {
      f4v st0 = __builtin_amdgcn_mfma_f32_16x16x32_bf16(kf0, qf, zf, 0, 0, 0);
      float p0[4], p1[4];
#pragma unroll
      for (int r = 0; r < 4; r++) p0[r] = __builtin_amdgcn_exp2f(st0[r]);
      if (qt & 1) {                 // slot0 full, slot1 = diagonal tile qt
        f4v st1 = __builtin_amdgcn_mfma_f32_16x16x32_bf16(kf1, qf, zf, 0, 0, 0);
#pragma unroll
        for (int r = 0; r < 4; r++) {
          float e = __builtin_amdgcn_exp2f(st1[r]);
          p1[r] = md[r] ? e : 0.f;
        }
      } else {                      // slot0 = diagonal tile qt, slot1 beyond
#pragma unroll
        for (int r = 0; r < 4; r++) {
          p0[r] = md[r] ? p0[r] : 0.f;
          p1[r] = 0.f;
        }
      }
      lsum += ((p0[0] + p0[1]) + (p0[2] + p0[3])) +
              ((p1[0] + p1[1]) + (p1[2] + p1[3]));
      union { unsigned u[4]; s8v s; } pu;
      pu.u[0] = cvtpk(p0[0], p0[1]);
      pu.u[1] = cvtpk(p0[2], p0[3]);
      pu.u[2] = cvtpk(p1[0], p1[1]);
      pu.u[3] = cvtpk(p1[2], p1[3]);
      oacc = __builtin_amdgcn_mfma_f32_16x16x32_bf16(pu.s, vf, oacc, 0, 0, 0);
    }

    // epilogue: reduce l per query, normalize, store O
    lsum += shx(lsum, 16);
    lsum += shx(lsum, 32);
    float inv = 1.0f / lsum;        // lane holds inv for query lq
    float invr[4];
#pragma unroll
    for (int r = 0; r < 4; r++) invr[r] = __shfl(inv, g4 + r, 64);
    if (real8) {
      float* ob = o + ((long)bh * Tc + q0 + g4) * 8 + lq;
#pragma unroll
      for (int r = 0; r < 4; r++) ob[r * 8] = oacc[r] * invr[r];
    }
  }
}

// ---------------------------------------------------------------------------
// 4-lane cooperative tail: read normalized O ; x += o@wo^T ; x += MLP(LN2)
// Lane roles (j = lane&3): A: head j&1 (O read, shfl swap);
// B: proj outputs c=4j..4j+3; C: MLP hidden units j*16..+15.
// ---------------------------------------------------------------------------
__device__ inline void coop_tail(
    const float* __restrict__ o,
    const float* swo, const float* sw1, const float* sw2,
    const float* sg2, const float* sb2, int bb, int tt, int j, float* xr) {
  // --- A: gather both heads' O rows via lane pair swap
  int hh = j & 1;
  int bh = bb * Hc + hh;
  const float4* op = (const float4*)(o + ((long)bh * Tc + tt) * 8);
  float4 a = op[0], b = op[1];
  float own[8] = {a.x, a.y, a.z, a.w, b.x, b.y, b.z, b.w};
  float oth[8];
#pragma unroll
  for (int s = 0; s < 8; s++) oth[s] = shx(own[s], 1);
  float orow[Cc];
#pragma unroll
  for (int s = 0; s < 8; s++) {
    orow[s]     = (hh == 0) ? own[s] : oth[s];
    orow[8 + s] = (hh == 0) ? oth[s] : own[s];
  }
  // --- B: proj, c = 4j..4j+3
  float xc[4];
#pragma unroll
  for (int qq = 0; qq < 4; qq++) {
    int c = 4 * j + qq;
    float acc = xr[c];
#pragma unroll
    for (int kk = 0; kk < Cc; kk++) acc += orow[kk] * swo[c * 17 + kk];
    xc[qq] = acc;
  }
  {
    float p[4];
#pragma unroll
    for (int qq = 0; qq < 4; qq++) p[qq] = shx(xc[qq], 1);
    bool lo = (j & 1) == 0;
    float a8[8], b8[8];
#pragma unroll
    for (int qq = 0; qq < 4; qq++) {
      a8[qq]     = lo ? xc[qq] : p[qq];
      a8[4 + qq] = lo ? p[qq] : xc[qq];
    }
#pragma unroll
    for (int s = 0; s < 8; s++) b8[s] = shx(a8[s], 2);
    bool lo2 = (j & 2) == 0;
#pragma unroll
    for (int s = 0; s < 8; s++) {
      xr[s]     = lo2 ? a8[s] : b8[s];
      xr[8 + s] = lo2 ? b8[s] : a8[s];
    }
  }
  // --- C: MLP, hidden units j*16..j*16+15
  float h[Cc];
  layernorm16(xr, h, sg2, sb2);
  float r[Cc];
#pragma unroll
  for (int c = 0; c < Cc; c++) r[c] = 0.f;
#pragma unroll
  for (int i = 0; i < 16; i++) {
    int jj = j * 16 + i;
    float acc = 0.f;
#pragma unroll
    for (int c = 0; c < Cc; c++) acc += h[c] * sw1[jj * 17 + c];
    acc = fmaxf(acc, 0.f);
#pragma unroll
    for (int c = 0; c < Cc; c++) r[c] += acc * sw2[c * 64 + jj];
  }
#pragma unroll
  for (int c = 0; c < Cc; c++) r[c] += shx(r[c], 1);
#pragma unroll
  for (int c = 0; c < Cc; c++) r[c] += shx(r[c], 2);
#pragma unroll
  for (int c = 0; c < Cc; c++) xr[c] += r[c];
}

// ---------------------------------------------------------------------------
// K3) layer-l epilogue + layer-(l+1) LN1+QKV (bf16 out)
// ---------------------------------------------------------------------------
__global__ __launch_bounds__(256, 4) void red_mid_kernel(
    const float* __restrict__ o,
    const float* __restrict__ wo, const float* __restrict__ g2,
    const float* __restrict__ b2, const float* __restrict__ w1,
    const float* __restrict__ w2,
    const float* __restrict__ wq, const float* __restrict__ wk,
    const float* __restrict__ wv, const float* __restrict__ g1,
    const float* __restrict__ b1,
    float* __restrict__ x, unsigned short* __restrict__ qb,
    unsigned short* __restrict__ kb, unsigned short* __restrict__ vt) {
  __shared__ float swo[16 * 17], sw1[64 * 17], sw2[1024];
  __shared__ float swq[256], swk[256], swv[256];
  __shared__ float sg2[Cc], sb2[Cc], sg1[Cc], sb1[Cc];
  int tid = threadIdx.x;
  swq[tid] = wq[tid]; swk[tid] = wk[tid]; swv[tid] = wv[tid];
  { int rr = tid >> 4, c = tid & 15; swo[rr * 17 + c] = wo[tid]; }
#pragma unroll
  for (int t = tid; t < 1024; t += 256) {
    int jj = t >> 4, c = t & 15;
    sw1[jj * 17 + c] = w1[t];
    sw2[t] = w2[t];
  }
  if (tid < Cc) {
    sg2[tid] = g2[tid]; sb2[tid] = b2[tid];
    sg1[tid] = g1[tid]; sb1[tid] = b1[tid];
  }
  __syncthreads();

  int tk = blockIdx.x * 64 + (tid >> 2);
  int j  = tid & 3;
  int bb = tk >> 11, tt = tk & (Tc - 1);
  float xr[Cc];
  const float4* xp = (const float4*)(x + (long)tk * Cc);
#pragma unroll
  for (int i = 0; i < 4; i++) {
    float4 a = xp[i];
    xr[4*i]=a.x; xr[4*i+1]=a.y; xr[4*i+2]=a.z; xr[4*i+3]=a.w;
  }
  coop_tail(o, swo, sw1, sw2, sg2, sb2, bb, tt, j, xr);
  ((float4*)(x + (long)tk * Cc))[j] =
      make_float4(xr[4*j], xr[4*j+1], xr[4*j+2], xr[4*j+3]);
  float h[Cc];
  layernorm16(xr, h, sg1, sb1);
  qkv_store_bf16(h, swq, swk, swv, bb, tt, j, qb, kb, vt);
}

// ---------------------------------------------------------------------------
// K5) final-layer epilogue + LNf + tied lm_head
// ---------------------------------------------------------------------------
__global__ __launch_bounds__(256, 4) void red_lnf_head_kernel(
    const float* __restrict__ o,
    const float* __restrict__ wo, const float* __restrict__ g2,
    const float* __restrict__ b2, const float* __restrict__ w1,
    const float* __restrict__ w2, const float* __restrict__ gf,
    const float* __restrict__ bf,
    const float* __restrict__ x, const float* __restrict__ tok,
    float* __restrict__ out) {
  __shared__ float swo[16 * 17], sw1[64 * 17], sw2[1024];
  __shared__ float sg2[Cc], sb2[Cc], sgf[Cc], sbf[Cc];
  __shared__ float sh[64 * Cc];
  int tid = threadIdx.x;
  { int rr = tid >> 4, c = tid & 15; swo[rr * 17 + c] = wo[tid]; }
#pragma unroll
  for (int t = tid; t < 1024; t += 256) {
    int jj = t >> 4, c = t & 15;
    sw1[jj * 17 + c] = w1[t];
    sw2[t] = w2[t];
  }
  if (tid < Cc) {
    sg2[tid] = g2[tid]; sb2[tid] = b2[tid];
    sgf[tid] = gf[tid]; sbf[tid] = bf[tid];
  }
  __syncthreads();

  int tk = blockIdx.x * 64 + (tid >> 2);
  int j  = tid & 3;
  int bb = tk >> 11, tt = tk & (Tc - 1);
  float xr[Cc];
  const float4* xp = (const float4*)(x + (long)tk * Cc);
#pragma unroll
  for (int i = 0; i < 4; i++) {
    float4 a = xp[i];
    xr[4*i]=a.x; xr[4*i+1]=a.y; xr[4*i+2]=a.z; xr[4*i+3]=a.w;
  }
  coop_tail(o, swo, sw1, sw2, sg2, sb2, bb, tt, j, xr);
  float h[Cc];
  layernorm16(xr, h, sgf, sbf);
  ((float4*)(sh + (tid >> 2) * Cc))[j] =
      make_float4(h[4*j], h[4*j+1], h[4*j+2], h[4*j+3]);
  __syncthreads();

  // head phase: thread = vocab id, 64 tokens from LDS (broadcast reads)
  float4 e0, e1, e2, e3;
  {
    const float4* ep = (const float4*)(tok + tid * Cc);
    e0 = ep[0]; e1 = ep[1]; e2 = ep[2]; e3 = ep[3];
  }
  int row0 = blockIdx.x * 64;
#pragma unroll 4
  for (int t = 0; t < 64; t++) {
    const float4* hp = (const float4*)(sh + t * Cc);
    float4 h0 = hp[0], h1 = hp[1], h2 = hp[2], h3 = hp[3];
    float acc = h0.x*e0.x + h0.y*e0.y + h0.z*e0.z + h0.w*e0.w
              + h1.x*e1.x + h1.y*e1.y + h1.z*e1.z + h1.w*e1.w
              + h2.x*e2.x + h2.y*e2.y + h2.z*e2.z + h2.w*e2.w
              + h3.x*e3.x + h3.y*e3.y + h3.z*e3.z + h3.w*e3.w;
    out[(long)(row0 + t) * Vc + tid] = acc;
  }
}

// ---------------------------------------------------------------------------
// launcher
// ---------------------------------------------------------------------------
extern "C" void kernel_launch(void* const* d_in, const int* in_sizes, int n_in,
                              void* d_out, int out_size, void* d_ws,
                              size_t ws_size, hipStream_t stream) {
  const int*   idx  = (const int*)  d_in[0];
  const float* tok  = (const float*)d_in[1];
  const float* pos  = (const float*)d_in[2];
  const float* wq   = (const float*)d_in[3];
  const float* wk   = (const float*)d_in[4];
  const float* wv   = (const float*)d_in[5];
  const float* wo   = (const float*)d_in[6];
  const float* ln1g = (const float*)d_in[7];
  const float* ln1b = (const float*)d_in[8];
  const float* ln2g = (const float*)d_in[9];
  const float* ln2b = (const float*)d_in[10];
  const float* w1   = (const float*)d_in[11];
  const float* w2   = (const float*)d_in[12];
  const float* lnfg = (const float*)d_in[13];
  const float* lnfb = (const float*)d_in[14];
  float* out = (float*)d_out;

  // workspace: x 2MB | o 2MB | qb 1MB | kb 1MB | vt 1MB | zp 64B
  float* x = (float*)d_ws;
  float* o = x + (long)BT * Cc;
  unsigned short* qb = (unsigned short*)(o + (long)Bc * Hc * Tc * HSc);
  unsigned short* kb = qb + (long)Bc * Hc * Tc * HSc;
  unsigned short* vt = kb + (long)Bc * Hc * Tc * HSc;
  unsigned short* zp = vt + (long)Bc * Hc * Tc * HSc;

  embed_ln_qkv_kernel<<<BT / 64, 256, 0, stream>>>(
      idx, tok, pos, wq, wk, wv, ln1g, ln1b, x, qb, kb, vt, zp);
  attn_kernel<<<2048, 64, 0, stream>>>(qb, kb, vt, zp, o);
  red_mid_kernel<<<BT / 64, 256, 0, stream>>>(
      o, wo, ln2g, ln2b, w1, w2,
      wq + Hc * Cc * HSc, wk + Hc * Cc * HSc, wv + Hc * Cc * HSc,
      ln1g + Cc, ln1b + Cc, x, qb, kb, vt);
  attn_kernel<<<2048, 64, 0, stream>>>(qb, kb, vt, zp, o);
  red_lnf_head_kernel<<<BT / 64, 256, 0, stream>>>(
      o, wo + Cc * Cc, ln2g + Cc, ln2b + Cc,
      w1 + 4 * Cc * Cc, w2 + 4 * Cc * Cc, lnfg, lnfb, x, tok, out);
}

// Round 9
// 170.264 us; speedup vs baseline: 1.7835x; 1.0079x over previous
//
#include <hip/hip_runtime.h>
#include <math.h>

// Problem constants (MicroGPT)
constexpr int Bc  = 16;
constexpr int Tc  = 2048;
constexpr int Cc  = 16;
constexpr int Hc  = 2;
constexpr int HSc = 8;
constexpr int Vc  = 256;
constexpr int BT  = Bc * Tc;          // 32768 tokens
constexpr float EPSc = 1e-5f;

// R6 (PASS, 171.6us): bf16 MFMA attention (16x16x32, swapped-QK, V-permuted
// for in-lane PV), single-stream, prefetched K/V, direct writes.
// R8 (FAIL, absmax 0.099): bundled dual-stream attn + LDS-staged vt.
// R9 = A/B isolation: attn reverted to EXACT R6 single-stream; ONLY the
// vt LDS staging kept (proven byte-identical layout). Pass -> dual-stream
// was the bug. Fail -> staging is the bug; full revert next.

typedef short s8v __attribute__((ext_vector_type(8)));  // 8 bf16 (A/B frag)
typedef float f4v __attribute__((ext_vector_type(4)));  // 4 f32  (C/D frag)

__device__ inline float shx(float v, int m) { return __shfl_xor(v, m, 64); }

__device__ inline unsigned short f2bf(float f) {        // f32 -> bf16 RNE
  union { float f; unsigned u; } c; c.f = f;
  unsigned u = c.u + 0x7fffu + ((c.u >> 16) & 1u);
  return (unsigned short)(u >> 16);
}

__device__ inline unsigned cvtpk(float a, float b) {    // pack 2 f32 -> 2 bf16
  unsigned r;
  asm("v_cvt_pk_bf16_f32 %0, %1, %2" : "=v"(r) : "v"(a), "v"(b));
  return r;
}

// ---------------------------------------------------------------------------
// LN helper
// ---------------------------------------------------------------------------
__device__ inline void layernorm16(const float* xr, float* h,
                                   const float* g, const float* b) {
  float m = 0.f;
#pragma unroll
  for (int c = 0; c < Cc; c++) m += xr[c];
  m *= (1.f / Cc);
  float var = 0.f;
#pragma unroll
  for (int c = 0; c < Cc; c++) { float d = xr[c] - m; var += d * d; }
  var *= (1.f / Cc);
  float rs = rsqrtf(var + EPSc);
#pragma unroll
  for (int c = 0; c < Cc; c++) h[c] = (xr[c] - m) * rs * g[c] + b[c];
}

// ---------------------------------------------------------------------------
// 4-lane-coop QKV -> bf16. Lane j computes s={2j,2j+1}.
// qb: [bh][T][8] bf16, Q pre-scaled by HS^-0.5*log2(e).  kb: [bh][T][8].
// V goes to LDS tile sv[2][8][64] (permuted cols); block writes vt rows
// coalesced afterwards. vt: [bh][8][T] bf16, cols permuted per 32-block:
// key a (local=a&31) stored at 8*((a&15)>>2) + 4*((a>>4)&1) + (a&3).
// ---------------------------------------------------------------------------
__device__ inline void qkv_store_bf16(const float* h, const float* swq,
                                      const float* swk, const float* swv,
                                      int bb, int tt, int j,
                                      unsigned short* __restrict__ qb,
                                      unsigned short* __restrict__ kb,
                                      unsigned short* sv) {
  const float pre = 0.35355339059327373f * 1.4426950408889634f;
  int a = tt & 31;
  int col = (tt & 32) | ((((a & 15) >> 2)) << 3) | (((a >> 4) & 1) << 2) |
            (a & 3);                  // 0..63 within the block's 64-col span
#pragma unroll
  for (int hh = 0; hh < Hc; hh++) {
    float q0 = 0.f, q1 = 0.f, k0 = 0.f, k1 = 0.f, v0 = 0.f, v1 = 0.f;
#pragma unroll
    for (int c = 0; c < Cc; c++) {
      float hv = h[c];
      const float* wqp = swq + (hh * Cc + c) * HSc + 2 * j;
      const float* wkp = swk + (hh * Cc + c) * HSc + 2 * j;
      const float* wvp = swv + (hh * Cc + c) * HSc + 2 * j;
      q0 += hv * wqp[0]; q1 += hv * wqp[1];
      k0 += hv * wkp[0]; k1 += hv * wkp[1];
      v0 += hv * wvp[0]; v1 += hv * wvp[1];
    }
    int bh = bb * Hc + hh;
    long rowb = ((long)bh * Tc + tt) * 8 + 2 * j;
    unsigned qp = (unsigned)f2bf(q0 * pre) | ((unsigned)f2bf(q1 * pre) << 16);
    unsigned kp = (unsigned)f2bf(k0) | ((unsigned)f2bf(k1) << 16);
    *(unsigned*)(qb + rowb) = qp;
    *(unsigned*)(kb + rowb) = kp;
    sv[(hh * 8 + 2 * j) * 64 + col]     = f2bf(v0);
    sv[(hh * 8 + 2 * j + 1) * 64 + col] = f2bf(v1);
  }
}

// block-level coalesced writeout of the staged V-transpose tile
__device__ inline void vt_writeout(const unsigned short* sv, int bb, int t0,
                                   int tid, unsigned short* __restrict__ vt) {
  int r  = tid >> 4;                  // row 0..15: hh = r>>3, d = r&7
  int cs = (tid & 15) * 4;            // short offset within 64-col row
  int bh = bb * Hc + (r >> 3);
  int d  = r & 7;
  *(uint2*)(vt + ((long)bh * 8 + d) * Tc + t0 + cs) =
      *(const uint2*)(sv + r * 64 + cs);
}

// ---------------------------------------------------------------------------
// K1) x = tok_emb[idx] + pos_emb ; h = LN1(x) ; qkv -> bf16 buffers.
//     Block 0 also zeroes the 64B pad region used for MFMA operand padding.
// ---------------------------------------------------------------------------
__global__ __launch_bounds__(256, 4) void embed_ln_qkv_kernel(
    const int* __restrict__ idx, const float* __restrict__ tok,
    const float* __restrict__ pos,
    const float* __restrict__ wq, const float* __restrict__ wk,
    const float* __restrict__ wv,
    const float* __restrict__ g, const float* __restrict__ b,
    float* __restrict__ x, unsigned short* __restrict__ qb,
    unsigned short* __restrict__ kb, unsigned short* __restrict__ vt,
    unsigned short* __restrict__ zp) {
  __shared__ float swq[256], swk[256], swv[256], sg[Cc], sb[Cc];
  __shared__ unsigned short sv[16 * 64];
  int tid = threadIdx.x;
  if (blockIdx.x == 0 && tid < 16) ((unsigned*)zp)[tid] = 0u;  // 64B zeros
  swq[tid] = wq[tid];
  swk[tid] = wk[tid];
  swv[tid] = wv[tid];
  if (tid < Cc) { sg[tid] = g[tid]; sb[tid] = b[tid]; }
  __syncthreads();

  int tk = blockIdx.x * 64 + (tid >> 2);
  int j  = tid & 3;
  int tt = tk & (Tc - 1);
  int bb = tk >> 11;
  int id = idx[tk];
  float xr[Cc];
  const float4* te = (const float4*)(tok + id * Cc);
  const float4* pe = (const float4*)(pos + tt * Cc);
#pragma unroll
  for (int i = 0; i < 4; i++) {
    float4 a = te[i], p = pe[i];
    xr[4*i] = a.x + p.x; xr[4*i+1] = a.y + p.y;
    xr[4*i+2] = a.z + p.z; xr[4*i+3] = a.w + p.w;
  }
  ((float4*)(x + (long)tk * Cc))[j] =
      make_float4(xr[4*j], xr[4*j+1], xr[4*j+2], xr[4*j+3]);
  float h[Cc];
  layernorm16(xr, h, sg, sb);
  qkv_store_bf16(h, swq, swk, swv, bb, tt, j, qb, kb, sv);
  __syncthreads();
  vt_writeout(sv, bb, (blockIdx.x * 64) & (Tc - 1), tid, vt);
}

// ---------------------------------------------------------------------------
// K2) MFMA causal flash attention — EXACT R6 single-stream version.
//     One wave (64-thr block) owns TWO q-tiles (qt, 127-qt) -> every wave
//     does exactly 65+1 32-key blocks. Per 32 keys: 2 QK MFMA (swapped:
//     D=S^T, lane l holds P for query l&15) + exp2 + cvt_pk + 1 PV MFMA
//     (in-lane P thanks to the V permutation). Unnormalized exp2 softmax,
//     diagonal masked only in last block. Writes normalized O[bh][T][8] f32.
// ---------------------------------------------------------------------------
__global__ __launch_bounds__(64, 4) void attn_kernel(
    const unsigned short* __restrict__ qb,
    const unsigned short* __restrict__ kb,
    const unsigned short* __restrict__ vt,
    const unsigned short* __restrict__ zp,
    float* __restrict__ o) {
  int pairId = blockIdx.x >> 5;     // 0..63
  int bh     = blockIdx.x & 31;
  int lane   = threadIdx.x;
  int lq     = lane & 15;
  int g4     = (lane >> 4) << 2;    // 4*(lane>>4)
  bool real16 = lane < 16;
  bool real8  = lq < 8;
  bool md[4];                       // diagonal mask: key-in-tile <= q-in-tile
#pragma unroll
  for (int r = 0; r < 4; r++) md[r] = (g4 + r) <= lq;

  const f4v zf = {0.f, 0.f, 0.f, 0.f};

#pragma unroll 1
  for (int hf = 0; hf < 2; hf++) {
    int qt = hf ? (127 - pairId) : pairId;
    int q0 = qt << 4;
    int NB = (qt + 2) >> 1;         // 32-key blocks; last contains diagonal

    // Q fragment (B-operand): lanes<16 load full bf16 row, others zeros.
    s8v qf = *(real16 ? (const s8v*)(qb + ((long)bh * Tc + q0 + lq) * 8)
                      : (const s8v*)zp);
    // K pointers (A-operand rows), zero-lanes pinned to pad (step 0).
    const unsigned short* kp_ = real16 ? kb + ((long)bh * Tc + lq) * 8
                                       : zp;
    long kts = real16 ? 128 : 0;    // ushorts per 16-key tile
    // V pointer (B-operand), d-row lq<8, k-block offset by lane group.
    const unsigned short* vp_ =
        real8 ? vt + ((long)bh * 8 + lq) * Tc + (g4 << 1) : zp;
    long vts = real8 ? 32 : 0;      // ushorts per 32-key block

    f4v oacc = zf;
    float lsum = 0.f;

    s8v kf0 = *(const s8v*)kp_;
    s8v kf1 = *(const s8v*)(kp_ + kts);
    kp_ += 2 * kts;
    s8v vf = *(const s8v*)vp_;
    vp_ += vts;

    for (int b = 0; b < NB - 1; b++) {
      s8v kn0 = *(const s8v*)kp_;
      s8v kn1 = *(const s8v*)(kp_ + kts);
      kp_ += 2 * kts;
      s8v vn = *(const s8v*)vp_;
      vp_ += vts;

      f4v st0 = __builtin_amdgcn_mfma_f32_16x16x32_bf16(kf0, qf, zf, 0, 0, 0);
      f4v st1 = __builtin_amdgcn_mfma_f32_16x16x32_bf16(kf1, qf, zf, 0, 0, 0);
      float p00 = __builtin_amdgcn_exp2f(st0[0]);
      float p01 = __builtin_amdgcn_exp2f(st0[1]);
      float p02 = __builtin_amdgcn_exp2f(st0[2]);
      float p03 = __builtin_amdgcn_exp2f(st0[3]);
      float p10 = __builtin_amdgcn_exp2f(st1[0]);
      float p11 = __builtin_amdgcn_exp2f(st1[1]);
      float p12 = __builtin_amdgcn_exp2f(st1[2]);
      float p13 = __builtin_amdgcn_exp2f(st1[3]);
      lsum += ((p00 + p01) + (p02 + p03)) + ((p10 + p11) + (p12 + p13));
      union { unsigned u[4]; s8v s; } pu;
      pu.u[0] = cvtpk(p00, p01);
      pu.u[1] = cvtpk(p02, p03);
      pu.u[2] = cvtpk(p10, p11);
      pu.u[3] = cvtpk(p12, p13);
      oacc = __builtin_amdgcn_mfma_f32_16x16x32_bf16(pu.s, vf, oacc, 0, 0, 0);
      kf0 = kn0; kf1 = kn1; vf = vn;
    }

    // last block: tile (qt&1 ? qt-1 : qt) in slot0, diagonal masking
    {
      f4v st0 = __builtin_amdgcn_mfma_f32_16x16x32_bf16(kf0, qf, zf, 0, 0, 0);
      float p0[4], p1[4];
#pragma unroll
      for (int r = 0; r < 4; r++) p0[r] = __builtin_amdgcn_exp2f(st0[r]);
      if (qt & 1) {                 // slot0 full, slot1 = diagonal tile qt
        f4v st1 = __builtin_amdgcn_mfma_f32_16x16x32_bf16(kf1, qf, zf, 0, 0, 0);
#pragma unroll
        for (int r = 0; r < 4; r++) {
          float e = __builtin_amdgcn_exp2f(st1[r]);
          p1[r] = md[r] ? e : 0.f;
        }
      } else {                      // slot0 = diagonal tile qt, slot1 beyond
#pragma unroll
        for (int r = 0; r < 4; r++) {
          p0[r] = md[r] ? p0[r] : 0.f;
          p1[r] = 0.f;
        }
      }
      lsum += ((p0[0] + p0[1]) + (p0[2] + p0[3])) +
              ((p1[0] + p1[1]) + (p1[2] + p1[3]));
      union { unsigned u[4]; s8v s; } pu;
      pu.u[0] = cvtpk(p0[0], p0[1]);
      pu.u[1] = cvtpk(p0[2], p0[3]);
      pu.u[2] = cvtpk(p1[0], p1[1]);
      pu.u[3] = cvtpk(p1[2], p1[3]);
      oacc = __builtin_amdgcn_mfma_f32_16x16x32_bf16(pu.s, vf, oacc, 0, 0, 0);
    }

    // epilogue: reduce l per query, normalize, store O
    lsum += shx(lsum, 16);
    lsum += shx(lsum, 32);
    float inv = 1.0f / lsum;        // lane holds inv for query lq
    float invr[4];
#pragma unroll
    for (int r = 0; r < 4; r++) invr[r] = __shfl(inv, g4 + r, 64);
    if (real8) {
      float* ob = o + ((long)bh * Tc + q0 + g4) * 8 + lq;
#pragma unroll
      for (int r = 0; r < 4; r++) ob[r * 8] = oacc[r] * invr[r];
    }
  }
}

// ---------------------------------------------------------------------------
// 4-lane cooperative tail: read normalized O ; x += o@wo^T ; x += MLP(LN2)
// Lane roles (j = lane&3): A: head j&1 (O read, shfl swap);
// B: proj outputs c=4j..4j+3; C: MLP hidden units j*16..+15.
// ---------------------------------------------------------------------------
__device__ inline void coop_tail(
    const float* __restrict__ o,
    const float* swo, const float* sw1, const float* sw2,
    const float* sg2, const float* sb2, int bb, int tt, int j, float* xr) {
  // --- A: gather both heads' O rows via lane pair swap
  int hh = j & 1;
  int bh = bb * Hc + hh;
  const float4* op = (const float4*)(o + ((long)bh * Tc + tt) * 8);
  float4 a = op[0], b = op[1];
  float own[8] = {a.x, a.y, a.z, a.w, b.x, b.y, b.z, b.w};
  float oth[8];
#pragma unroll
  for (int s = 0; s < 8; s++) oth[s] = shx(own[s], 1);
  float orow[Cc];
#pragma unroll
  for (int s = 0; s < 8; s++) {
    orow[s]     = (hh == 0) ? own[s] : oth[s];
    orow[8 + s] = (hh == 0) ? oth[s] : own[s];
  }
  // --- B: proj, c = 4j..4j+3
  float xc[4];
#pragma unroll
  for (int qq = 0; qq < 4; qq++) {
    int c = 4 * j + qq;
    float acc = xr[c];
#pragma unroll
    for (int kk = 0; kk < Cc; kk++) acc += orow[kk] * swo[c * 17 + kk];
    xc[qq] = acc;
  }
  {
    float p[4];
#pragma unroll
    for (int qq = 0; qq < 4; qq++) p[qq] = shx(xc[qq], 1);
    bool lo = (j & 1) == 0;
    float a8[8], b8[8];
#pragma unroll
    for (int qq = 0; qq < 4; qq++) {
      a8[qq]     = lo ? xc[qq] : p[qq];
      a8[4 + qq] = lo ? p[qq] : xc[qq];
    }
#pragma unroll
    for (int s = 0; s < 8; s++) b8[s] = shx(a8[s], 2);
    bool lo2 = (j & 2) == 0;
#pragma unroll
    for (int s = 0; s < 8; s++) {
      xr[s]     = lo2 ? a8[s] : b8[s];
      xr[8 + s] = lo2 ? b8[s] : a8[s];
    }
  }
  // --- C: MLP, hidden units j*16..j*16+15
  float h[Cc];
  layernorm16(xr, h, sg2, sb2);
  float r[Cc];
#pragma unroll
  for (int c = 0; c < Cc; c++) r[c] = 0.f;
#pragma unroll
  for (int i = 0; i < 16; i++) {
    int jj = j * 16 + i;
    float acc = 0.f;
#pragma unroll
    for (int c = 0; c < Cc; c++) acc += h[c] * sw1[jj * 17 + c];
    acc = fmaxf(acc, 0.f);
#pragma unroll
    for (int c = 0; c < Cc; c++) r[c] += acc * sw2[c * 64 + jj];
  }
#pragma unroll
  for (int c = 0; c < Cc; c++) r[c] += shx(r[c], 1);
#pragma unroll
  for (int c = 0; c < Cc; c++) r[c] += shx(r[c], 2);
#pragma unroll
  for (int c = 0; c < Cc; c++) xr[c] += r[c];
}

// ---------------------------------------------------------------------------
// K3) layer-l epilogue + layer-(l+1) LN1+QKV (bf16 out)
// ---------------------------------------------------------------------------
__global__ __launch_bounds__(256, 4) void red_mid_kernel(
    const float* __restrict__ o,
    const float* __restrict__ wo, const float* __restrict__ g2,
    const float* __restrict__ b2, const float* __restrict__ w1,
    const float* __restrict__ w2,
    const float* __restrict__ wq, const float* __restrict__ wk,
    const float* __restrict__ wv, const float* __restrict__ g1,
    const float* __restrict__ b1,
    float* __restrict__ x, unsigned short* __restrict__ qb,
    unsigned short* __restrict__ kb, unsigned short* __restrict__ vt) {
  __shared__ float swo[16 * 17], sw1[64 * 17], sw2[1024];
  __shared__ float swq[256], swk[256], swv[256];
  __shared__ float sg2[Cc], sb2[Cc], sg1[Cc], sb1[Cc];
  __shared__ unsigned short sv[16 * 64];
  int tid = threadIdx.x;
  swq[tid] = wq[tid]; swk[tid] = wk[tid]; swv[tid] = wv[tid];
  { int rr = tid >> 4, c = tid & 15; swo[rr * 17 + c] = wo[tid]; }
#pragma unroll
  for (int t = tid; t < 1024; t += 256) {
    int jj = t >> 4, c = t & 15;
    sw1[jj * 17 + c] = w1[t];
    sw2[t] = w2[t];
  }
  if (tid < Cc) {
    sg2[tid] = g2[tid]; sb2[tid] = b2[tid];
    sg1[tid] = g1[tid]; sb1[tid] = b1[tid];
  }
  __syncthreads();

  int tk = blockIdx.x * 64 + (tid >> 2);
  int j  = tid & 3;
  int bb = tk >> 11, tt = tk & (Tc - 1);
  float xr[Cc];
  const float4* xp = (const float4*)(x + (long)tk * Cc);
#pragma unroll
  for (int i = 0; i < 4; i++) {
    float4 a = xp[i];
    xr[4*i]=a.x; xr[4*i+1]=a.y; xr[4*i+2]=a.z; xr[4*i+3]=a.w;
  }
  coop_tail(o, swo, sw1, sw2, sg2, sb2, bb, tt, j, xr);
  ((float4*)(x + (long)tk * Cc))[j] =
      make_float4(xr[4*j], xr[4*j+1], xr[4*j+2], xr[4*j+3]);
  float h[Cc];
  layernorm16(xr, h, sg1, sb1);
  qkv_store_bf16(h, swq, swk, swv, bb, tt, j, qb, kb, sv);
  __syncthreads();
  vt_writeout(sv, bb, (blockIdx.x * 64) & (Tc - 1), tid, vt);
}

// ---------------------------------------------------------------------------
// K5) final-layer epilogue + LNf + tied lm_head
// ---------------------------------------------------------------------------
__global__ __launch_bounds__(256, 4) void red_lnf_head_kernel(
    const float* __restrict__ o,
    const float* __restrict__ wo, const float* __restrict__ g2,
    const float* __restrict__ b2, const float* __restrict__ w1,
    const float* __restrict__ w2, const float* __restrict__ gf,
    const float* __restrict__ bf,
    const float* __restrict__ x, const float* __restrict__ tok,
    float* __restrict__ out) {
  __shared__ float swo[16 * 17], sw1[64 * 17], sw2[1024];
  __shared__ float sg2[Cc], sb2[Cc], sgf[Cc], sbf[Cc];
  __shared__ float sh[64 * Cc];
  int tid = threadIdx.x;
  { int rr = tid >> 4, c = tid & 15; swo[rr * 17 + c] = wo[tid]; }
#pragma unroll
  for (int t = tid; t < 1024; t += 256) {
    int jj = t >> 4, c = t & 15;
    sw1[jj * 17 + c] = w1[t];
    sw2[t] = w2[t];
  }
  if (tid < Cc) {
    sg2[tid] = g2[tid]; sb2[tid] = b2[tid];
    sgf[tid] = gf[tid]; sbf[tid] = bf[tid];
  }
  __syncthreads();

  int tk = blockIdx.x * 64 + (tid >> 2);
  int j  = tid & 3;
  int bb = tk >> 11, tt = tk & (Tc - 1);
  float xr[Cc];
  const float4* xp = (const float4*)(x + (long)tk * Cc);
#pragma unroll
  for (int i = 0; i < 4; i++) {
    float4 a = xp[i];
    xr[4*i]=a.x; xr[4*i+1]=a.y; xr[4*i+2]=a.z; xr[4*i+3]=a.w;
  }
  coop_tail(o, swo, sw1, sw2, sg2, sb2, bb, tt, j, xr);
  float h[Cc];
  layernorm16(xr, h, sgf, sbf);
  ((float4*)(sh + (tid >> 2) * Cc))[j] =
      make_float4(h[4*j], h[4*j+1], h[4*j+2], h[4*j+3]);
  __syncthreads();

  // head phase: thread = vocab id, 64 tokens from LDS (broadcast reads)
  float4 e0, e1, e2, e3;
  {
    const float4* ep = (const float4*)(tok + tid * Cc);
    e0 = ep[0]; e1 = ep[1]; e2 = ep[2]; e3 = ep[3];
  }
  int row0 = blockIdx.x * 64;
#pragma unroll 4
  for (int t = 0; t < 64; t++) {
    const float4* hp = (const float4*)(sh + t * Cc);
    float4 h0 = hp[0], h1 = hp[1], h2 = hp[2], h3 = hp[3];
    float acc = h0.x*e0.x + h0.y*e0.y + h0.z*e0.z + h0.w*e0.w
              + h1.x*e1.x + h1.y*e1.y + h1.z*e1.z + h1.w*e1.w
              + h2.x*e2.x + h2.y*e2.y + h2.z*e2.z + h2.w*e2.w
              + h3.x*e3.x + h3.y*e3.y + h3.z*e3.z + h3.w*e3.w;
    out[(long)(row0 + t) * Vc + tid] = acc;
  }
}

// ---------------------------------------------------------------------------
// launcher
// ---------------------------------------------------------------------------
extern "C" void kernel_launch(void* const* d_in, const int* in_sizes, int n_in,
                              void* d_out, int out_size, void* d_ws,
                              size_t ws_size, hipStream_t stream) {
  const int*   idx  = (const int*)  d_in[0];
  const float* tok  = (const float*)d_in[1];
  const float* pos  = (const float*)d_in[2];
  const float* wq   = (const float*)d_in[3];
  const float* wk   = (const float*)d_in[4];
  const float* wv   = (const float*)d_in[5];
  const float* wo   = (const float*)d_in[6];
  const float* ln1g = (const float*)d_in[7];
  const float* ln1b = (const float*)d_in[8];
  const float* ln2g = (const float*)d_in[9];
  const float* ln2b = (const float*)d_in[10];
  const float* w1   = (const float*)d_in[11];
  const float* w2   = (const float*)d_in[12];
  const float* lnfg = (const float*)d_in[13];
  const float* lnfb = (const float*)d_in[14];
  float* out = (float*)d_out;

  // workspace: x 2MB | o 2MB | qb 1MB | kb 1MB | vt 1MB | zp 64B
  float* x = (float*)d_ws;
  float* o = x + (long)BT * Cc;
  unsigned short* qb = (unsigned short*)(o + (long)Bc * Hc * Tc * HSc);
  unsigned short* kb = qb + (long)Bc * Hc * Tc * HSc;
  unsigned short* vt = kb + (long)Bc * Hc * Tc * HSc;
  unsigned short* zp = vt + (long)Bc * Hc * Tc * HSc;

  embed_ln_qkv_kernel<<<BT / 64, 256, 0, stream>>>(
      idx, tok, pos, wq, wk, wv, ln1g, ln1b, x, qb, kb, vt, zp);
  attn_kernel<<<2048, 64, 0, stream>>>(qb, kb, vt, zp, o);
  red_mid_kernel<<<BT / 64, 256, 0, stream>>>(
      o, wo, ln2g, ln2b, w1, w2,
      wq + Hc * Cc * HSc, wk + Hc * Cc * HSc, wv + Hc * Cc * HSc,
      ln1g + Cc, ln1b + Cc, x, qb, kb, vt);
  attn_kernel<<<2048, 64, 0, stream>>>(qb, kb, vt, zp, o);
  red_lnf_head_kernel<<<BT / 64, 256, 0, stream>>>(
      o, wo + Cc * Cc, ln2g + Cc, ln2b + Cc,
      w1 + 4 * Cc * Cc, w2 + 4 * Cc * Cc, lnfg, lnfb, x, tok, out);
}